// Round 1
// 1677.012 us; speedup vs baseline: 3.2686x; 3.2686x over previous
//
#include <hip/hip_runtime.h>
#include <hip/hip_bf16.h>
#include <math.h>

// Problem constants
#define Bb 4
#define Nn 4096
#define Hh 16
#define DHh 64
#define Mm 266
#define Dd 1024
#define BHh (Bb*Hh)

#define DN_SCALE 0.35355339059327373f   // 64^-0.25
#define RATIO 0.06131393394849658f      // 266^-0.5
#define EPS_FAVOR 1e-4f
#define EPS_LN 1e-5f

typedef __attribute__((ext_vector_type(8))) short frag_t;   // 8 x bf16
typedef __attribute__((ext_vector_type(4))) short sh4;      // 4 x bf16
typedef __attribute__((ext_vector_type(4))) float f32x4;

__device__ __forceinline__ ushort f2bf(float f) {
    unsigned u = __float_as_uint(f);
    return (ushort)((u + 0x7FFFu + ((u >> 16) & 1u)) >> 16);
}
__device__ __forceinline__ float bf2f(ushort h) {
    return __uint_as_float(((unsigned)h) << 16);
}
__device__ __forceinline__ unsigned fenc(float f) {
    unsigned u = __float_as_uint(f);
    return (u & 0x80000000u) ? ~u : (u | 0x80000000u);
}
__device__ __forceinline__ float fdec(unsigned e) {
    unsigned u = (e & 0x80000000u) ? (e ^ 0x80000000u) : ~e;
    return __uint_as_float(u);
}
__device__ __forceinline__ void gld16(const void* g, void* l) {
    __builtin_amdgcn_global_load_lds((const __attribute__((address_space(1))) unsigned int*)g,
                                     (__attribute__((address_space(3))) unsigned int*)l, 16, 0, 0);
}

// ---------------------------------------------------------------------------
// prep: x fp32 -> bf16
// ---------------------------------------------------------------------------
__global__ __launch_bounds__(256) void conv_x_kernel(const float* __restrict__ x,
                                                     ushort* __restrict__ xb) {
    size_t i = ((size_t)blockIdx.x * 256 + threadIdx.x) * 8;
    float4 f0 = *(const float4*)(x + i);
    float4 f1 = *(const float4*)(x + i + 4);
    uint4 o;
    o.x = (unsigned)f2bf(f0.x) | ((unsigned)f2bf(f0.y) << 16);
    o.y = (unsigned)f2bf(f0.z) | ((unsigned)f2bf(f0.w) << 16);
    o.z = (unsigned)f2bf(f1.x) | ((unsigned)f2bf(f1.y) << 16);
    o.w = (unsigned)f2bf(f1.z) | ((unsigned)f2bf(f1.w) << 16);
    *(uint4*)(xb + i) = o;
}

// prep: W[k][n] fp32 -> WT[n][k] bf16 (K-contiguous for the B^T GEMM)
__global__ __launch_bounds__(256) void conv_wt_kernel(
    const float* __restrict__ Wq, const float* __restrict__ Wk,
    const float* __restrict__ Wv, const float* __restrict__ Wo,
    ushort* __restrict__ Tq, ushort* __restrict__ Tk,
    ushort* __restrict__ Tv, ushort* __restrict__ To) {
    const int z = blockIdx.z;
    const float* W = z == 0 ? Wq : z == 1 ? Wk : z == 2 ? Wv : Wo;
    ushort* WT = z == 0 ? Tq : z == 1 ? Tk : z == 2 ? Tv : To;
    __shared__ float tls[64][65];
    const int tid = threadIdx.x;
    const int n0 = blockIdx.x * 64, k0 = blockIdx.y * 64;
    const int r = tid >> 2, seg = tid & 3;
#pragma unroll
    for (int i = 0; i < 4; ++i) {
        float4 f = *(const float4*)(W + (size_t)(k0 + r) * 1024 + n0 + seg * 16 + i * 4);
        tls[r][seg * 16 + i * 4 + 0] = f.x;
        tls[r][seg * 16 + i * 4 + 1] = f.y;
        tls[r][seg * 16 + i * 4 + 2] = f.z;
        tls[r][seg * 16 + i * 4 + 3] = f.w;
    }
    __syncthreads();
    const int nl = tid >> 2;
#pragma unroll
    for (int i = 0; i < 16; ++i)
        WT[(size_t)(n0 + nl) * 1024 + k0 + seg * 16 + i] = f2bf(tls[seg * 16 + i][nl]);
}

// prep: proj fp32 [266][64] -> bf16 hi/lo [320][128], zero-padded rows
__global__ __launch_bounds__(256) void conv_proj_kernel(const float* __restrict__ proj,
                                                        ushort* __restrict__ pb) {
    const int idx = blockIdx.x * 256 + threadIdx.x;   // 320*64 = 20480
    const int m = idx >> 6, k = idx & 63;
    float v = (m < Mm) ? proj[m * 64 + k] : 0.f;
    ushort hi = f2bf(v);
    float lo = v - bf2f(hi);
    pb[m * 128 + k] = hi;
    pb[m * 128 + 64 + k] = f2bf(lo);
}

// prep: v head-major [bh][n][64] -> vT [bh][64][4096] bf16
__global__ __launch_bounds__(256) void transpose_v_kernel(const ushort* __restrict__ vv,
                                                          ushort* __restrict__ vT) {
    const int bh = blockIdx.y;
    const int n0 = blockIdx.x * 64;
    __shared__ ushort tls[64 * 72];
    const int tid = threadIdx.x;
    const int r = tid >> 2, s = tid & 3;
    *(frag_t*)&tls[r * 72 + s * 16] =
        *(const frag_t*)(vv + ((size_t)bh * Nn + n0 + r) * 64 + s * 16);
    *(frag_t*)&tls[r * 72 + s * 16 + 8] =
        *(const frag_t*)(vv + ((size_t)bh * Nn + n0 + r) * 64 + s * 16 + 8);
    __syncthreads();
    const int d = tid >> 2, s2 = tid & 3;
    frag_t o0, o1;
#pragma unroll
    for (int i = 0; i < 8; ++i) o0[i] = (short)tls[(s2 * 16 + i) * 72 + d];
#pragma unroll
    for (int i = 0; i < 8; ++i) o1[i] = (short)tls[(s2 * 16 + 8 + i) * 72 + d];
    *(frag_t*)(vT + ((size_t)bh * 64 + d) * Nn + n0 + s2 * 16) = o0;
    *(frag_t*)(vT + ((size_t)bh * 64 + d) * Nn + n0 + s2 * 16 + 8) = o1;
}

// prep: diag[bh*4096+n] = 0.5 * sum_k kb[n][k]^2
__global__ __launch_bounds__(256) void diag_kernel(const ushort* __restrict__ kb,
                                                   float* __restrict__ dg) {
    const size_t i = (size_t)blockIdx.x * 256 + threadIdx.x;
    const ushort* p = kb + i * 64;
    float s = 0.f;
#pragma unroll
    for (int seg = 0; seg < 8; ++seg) {
        frag_t a = *(const frag_t*)(p + seg * 8);
#pragma unroll
        for (int j = 0; j < 8; ++j) { float f = bf2f((ushort)a[j]); s += f * f; }
    }
    dg[i] = 0.5f * s;
}

// ---------------------------------------------------------------------------
// bf16 MFMA GEMM (m97 pattern): C[16384,1024] = A @ WT^T
// mode 0: head-major bf16 out (z selects W/out/scale)  mode 1: fp32 +bias+resid
// ---------------------------------------------------------------------------
__global__ __launch_bounds__(256) void gemm_bt(
    const ushort* __restrict__ A,
    const ushort* __restrict__ W0, const ushort* __restrict__ W1, const ushort* __restrict__ W2,
    ushort* __restrict__ o0, ushort* __restrict__ o1, ushort* __restrict__ o2,
    const float* __restrict__ bo, const float* __restrict__ xres, float* __restrict__ yres,
    int mode)
{
    __shared__ ushort As[128 * 32];
    __shared__ ushort Bs[128 * 32];
    const int tid = threadIdx.x;
    const int lane = tid & 63, w = tid >> 6;
    const int q = lane >> 4, m16 = lane & 15;
    const int wm = w & 1, wn = w >> 1;
    const int by = blockIdx.x, bx = blockIdx.y, z = blockIdx.z;
    const int row0 = by * 128, col0 = bx * 128;
    const ushort* WT = (mode == 0) ? (z == 0 ? W0 : z == 1 ? W1 : W2) : W0;

    f32x4 acc[4][4];
#pragma unroll
    for (int i = 0; i < 4; ++i)
#pragma unroll
        for (int j = 0; j < 4; ++j) acc[i][j] = (f32x4){0.f, 0.f, 0.f, 0.f};

    const int srow = lane >> 2;
    const int sseg = lane & 3;
    const int c0i = w * 2;

    for (int k0 = 0; k0 < 1024; k0 += 32) {
        __syncthreads();
#pragma unroll
        for (int c = 0; c < 2; ++c) {
            int idx = c0i + c;
            int ra = idx * 16 + srow;
            gld16(A  + (size_t)(row0 + ra) * 1024 + k0 + sseg * 8, (void*)(As + idx * 512 + lane * 8));
            gld16(WT + (size_t)(col0 + ra) * 1024 + k0 + sseg * 8, (void*)(Bs + idx * 512 + lane * 8));
        }
        __syncthreads();
        frag_t af[4], bf[4];
#pragma unroll
        for (int t = 0; t < 4; ++t) {
            af[t] = *(const frag_t*)&As[(wm * 64 + t * 16 + m16) * 32 + q * 8];
            bf[t] = *(const frag_t*)&Bs[(wn * 64 + t * 16 + m16) * 32 + q * 8];
        }
#pragma unroll
        for (int i = 0; i < 4; ++i)
#pragma unroll
            for (int j = 0; j < 4; ++j)
                acc[i][j] = __builtin_amdgcn_mfma_f32_16x16x32_bf16(af[i], bf[j], acc[i][j], 0, 0, 0);
    }

    if (mode == 0) {
        const float scale = (z < 2) ? DN_SCALE : 1.0f;
        ushort* outp = z == 0 ? o0 : z == 1 ? o1 : o2;
#pragma unroll
        for (int i = 0; i < 4; ++i)
#pragma unroll
            for (int j = 0; j < 4; ++j)
#pragma unroll
                for (int r = 0; r < 4; ++r) {
                    int row = row0 + wm * 64 + i * 16 + q * 4 + r;
                    int col = col0 + wn * 64 + j * 16 + m16;
                    int b = row >> 12, n = row & 4095;
                    int h = col >> 6, dh = col & 63;
                    outp[((size_t)((b << 4) + h) * 4096 + n) * 64 + dh] = f2bf(acc[i][j][r] * scale);
                }
    } else {
#pragma unroll
        for (int i = 0; i < 4; ++i)
#pragma unroll
            for (int j = 0; j < 4; ++j)
#pragma unroll
                for (int r = 0; r < 4; ++r) {
                    int row = row0 + wm * 64 + i * 16 + q * 4 + r;
                    int col = col0 + wn * 64 + j * 16 + m16;
                    size_t off = (size_t)row * 1024 + col;
                    yres[off] = acc[i][j][r] + bo[col] + xres[off];
                }
    }
}

// ---------------------------------------------------------------------------
// k-stab: per (b,h) max over (n,m) of ks[n,:]·proj[m,:]
// ---------------------------------------------------------------------------
__global__ __launch_bounds__(256) void kstab_kernel(
    const ushort* __restrict__ ks, const float* __restrict__ proj,
    unsigned* __restrict__ stab_enc)
{
    const int bh = blockIdx.x;
    const int n0 = blockIdx.y * 64;
    const int tid = threadIdx.x;

    __shared__ float kt[64][65];
    __shared__ float red[256];

#pragma unroll
    for (int t = 0; t < 4; ++t) {
        int fi = tid + t * 256;
        int r = fi >> 4, k4 = (fi & 15) << 2;
        ushort4 a = *(const ushort4*)(ks + ((size_t)(bh * Nn) + n0 + r) * DHh + k4);
        kt[r][k4 + 0] = bf2f(a.x); kt[r][k4 + 1] = bf2f(a.y);
        kt[r][k4 + 2] = bf2f(a.z); kt[r][k4 + 3] = bf2f(a.w);
    }
    __syncthreads();

    float mx = -3.0e38f;
    for (int idx = tid; idx < 64 * Mm; idx += 256) {
        int n = idx & 63, m = idx >> 6;
        const float* pr = proj + m * DHh;
        float s = 0.f;
#pragma unroll 8
        for (int k = 0; k < 64; ++k) s += kt[n][k] * pr[k];
        mx = fmaxf(mx, s);
    }
    red[tid] = mx;
    __syncthreads();
    for (int off = 128; off > 0; off >>= 1) {
        if (tid < off) red[tid] = fmaxf(red[tid], red[tid + off]);
        __syncthreads();
    }
    if (tid == 0) atomicMax(stab_enc + bh, fenc(red[0]));
}

// ---------------------------------------------------------------------------
// ctx via MFMA: per n-tile of 32:
//   feature GEMM  S[32n][64m] = ks @ projT (hi+lo bf16, K=64 each)
//   epilogue      kf = RATIO*(exp(S-diag-kst)+EPS), pack bf16 -> kfT LDS
//   ctx GEMM      ctx[64m][64d] += kfT @ vT^T  (K=32)
// grid: (5 mchunks, 4 nsplits, 64 bh), block 256 (4 waves)
// ---------------------------------------------------------------------------
__global__ __launch_bounds__(256) void ctx_mfma_kernel(
    const ushort* __restrict__ kb, const ushort* __restrict__ vT,
    const ushort* __restrict__ pb, const float* __restrict__ diagk,
    const unsigned* __restrict__ stab_enc,
    float* __restrict__ ctx, float* __restrict__ ksum)
{
    const int m0 = blockIdx.x * 64;
    const int nb = blockIdx.y;
    const int bh = blockIdx.z;
    const int tid = threadIdx.x;
    const int lane = tid & 63, w = tid >> 6;
    const int q = lane >> 4, m16 = lane & 15;
    const float kst = fdec(stab_enc[bh]);

    // padded strides (ushorts): rows stay 16B-aligned, start-bank rotates
    __shared__ ushort ks_s[32 * 72];    // [32 n][64 k], stride 72
    __shared__ ushort pj_s[64 * 136];   // [64 m][128 k hi|lo], stride 136
    __shared__ ushort kf_s[64 * 40];    // [64 m][32 n], stride 40
    __shared__ ushort vt_s[64 * 40];    // [64 d][32 n], stride 40
    __shared__ float  diag_s[32];

    // stage proj chunk once (hi|lo)
    for (int u = tid; u < 1024; u += 256) {
        int r = u >> 4, c = (u & 15) * 8;
        *(frag_t*)&pj_s[r * 136 + c] = *(const frag_t*)(pb + (size_t)(m0 + r) * 128 + c);
    }

    f32x4 acc_c[4];
#pragma unroll
    for (int j = 0; j < 4; ++j) acc_c[j] = (f32x4){0.f, 0.f, 0.f, 0.f};
    float ksacc[2] = {0.f, 0.f};

    const int tn  = w & 1;           // feature n-subtile of this wave
    const int tmb = (w >> 1) * 2;    // first feature m-tile of this wave

    const int srow_k = tid >> 3, sseg_k = tid & 7;   // ks: 32 rows x 8 segs
    const int srow_v = tid >> 2, sseg_v = tid & 3;   // vT: 64 rows x 4 segs
    const size_t kbase = ((size_t)bh * Nn + nb * 1024 + srow_k) * 64 + sseg_k * 8;
    const size_t vbase = ((size_t)bh * 64 + srow_v) * Nn + nb * 1024 + sseg_v * 8;
    const float* dgp = diagk + (size_t)bh * Nn + nb * 1024;

    frag_t kreg = *(const frag_t*)(kb + kbase);
    frag_t vreg = *(const frag_t*)(vT + vbase);
    float4 dreg;
    if (tid < 8) dreg = *(const float4*)(dgp + tid * 4);

    for (int t = 0; t < 32; ++t) {
        __syncthreads();                                  // prev tile fully consumed
        *(frag_t*)&ks_s[srow_k * 72 + sseg_k * 8] = kreg;
        *(frag_t*)&vt_s[srow_v * 40 + sseg_v * 8] = vreg;
        if (tid < 8) *(float4*)&diag_s[tid * 4] = dreg;
        __syncthreads();                                  // tile staged
        if (t < 31) {                                     // prefetch next tile
            kreg = *(const frag_t*)(kb + kbase + (size_t)(t + 1) * 2048);
            vreg = *(const frag_t*)(vT + vbase + (size_t)(t + 1) * 32);
            if (tid < 8) dreg = *(const float4*)(dgp + (t + 1) * 32 + tid * 4);
        }

        // ---- feature GEMM: rows n (A=ks), cols m (B=proj hi|lo) ----
        f32x4 sa[2];
        sa[0] = (f32x4){0.f, 0.f, 0.f, 0.f};
        sa[1] = (f32x4){0.f, 0.f, 0.f, 0.f};
#pragma unroll
        for (int s = 0; s < 2; ++s) {
            frag_t a = *(const frag_t*)&ks_s[(tn * 16 + m16) * 72 + s * 32 + q * 8];
#pragma unroll
            for (int jj = 0; jj < 2; ++jj) {
                const ushort* prow = &pj_s[((tmb + jj) * 16 + m16) * 136 + s * 32 + q * 8];
                frag_t bhi = *(const frag_t*)prow;
                frag_t blo = *(const frag_t*)(prow + 64);
                sa[jj] = __builtin_amdgcn_mfma_f32_16x16x32_bf16(a, bhi, sa[jj], 0, 0, 0);
                sa[jj] = __builtin_amdgcn_mfma_f32_16x16x32_bf16(a, blo, sa[jj], 0, 0, 0);
            }
        }

        // ---- epilogue: kf = mask * RATIO*(exp(S - diag - kst) + EPS) ----
#pragma unroll
        for (int jj = 0; jj < 2; ++jj) {
            int m_l = (tmb + jj) * 16 + m16;
            bool valid = (m0 + m_l) < Mm;
            sh4 pk;
            float vsum = 0.f;
#pragma unroll
            for (int r = 0; r < 4; ++r) {
                int n_l = tn * 16 + q * 4 + r;
                float val = valid ? RATIO * (__expf(sa[jj][r] - diag_s[n_l] - kst) + EPS_FAVOR) : 0.f;
                ushort hb = f2bf(val);
                pk[r] = (short)hb;
                vsum += bf2f(hb);
            }
            ksacc[jj] += vsum;
            *(sh4*)&kf_s[m_l * 40 + tn * 16 + q * 4] = pk;
        }
        __syncthreads();                                  // kfT ready

        // ---- ctx GEMM: rows m (A=kfT), cols d (B=vT), K = 32 n ----
        {
            frag_t a = *(const frag_t*)&kf_s[(w * 16 + m16) * 40 + q * 8];
#pragma unroll
            for (int j = 0; j < 4; ++j) {
                frag_t b = *(const frag_t*)&vt_s[(j * 16 + m16) * 40 + q * 8];
                acc_c[j] = __builtin_amdgcn_mfma_f32_16x16x32_bf16(a, b, acc_c[j], 0, 0, 0);
            }
        }
    }

    // ctx out: row m = w*16 + q*4 + r, col d = j*16 + m16
#pragma unroll
    for (int j = 0; j < 4; ++j)
#pragma unroll
        for (int r = 0; r < 4; ++r) {
            int m = m0 + w * 16 + q * 4 + r;
            if (m < Mm)
                atomicAdd(&ctx[((size_t)bh * Mm + m) * 64 + j * 16 + m16], acc_c[j][r]);
        }
    // ksum: reduce lane-partials over q groups (n coverage), then atomic
#pragma unroll
    for (int jj = 0; jj < 2; ++jj) {
        float v = ksacc[jj];
        v += __shfl_xor(v, 16);
        v += __shfl_xor(v, 32);
        int m = m0 + (tmb + jj) * 16 + m16;
        if (q == 0 && m < Mm) atomicAdd(&ksum[(size_t)bh * Mm + m], v);
    }
}

// ---------------------------------------------------------------------------
// q-side: features -> stab -> exp -> d_inv -> attn = (qf @ ctx) * d_inv
// ---------------------------------------------------------------------------
__global__ __launch_bounds__(256) void qout_kernel(
    const ushort* __restrict__ qs, const float* __restrict__ proj,
    const float* __restrict__ ctx, const float* __restrict__ ksum,
    ushort* __restrict__ attnb)
{
    const int n0 = blockIdx.x * 32;
    const int bh = blockIdx.y;
    const int b = bh >> 4, h = bh & 15;
    const int tid = threadIdx.x;

    __shared__ float qt[32][65];
    __shared__ float qf[32][267];
    __shared__ float diag[32], stab[32], dinv[32];
    __shared__ float red[256];

#pragma unroll
    for (int t = 0; t < 2; ++t) {
        int fi = tid + t * 256;
        int r = fi >> 4, k4 = (fi & 15) << 2;
        ushort4 a = *(const ushort4*)(qs + ((size_t)(bh * Nn) + n0 + r) * DHh + k4);
        qt[r][k4 + 0] = bf2f(a.x); qt[r][k4 + 1] = bf2f(a.y);
        qt[r][k4 + 2] = bf2f(a.z); qt[r][k4 + 3] = bf2f(a.w);
    }
    __syncthreads();
    if (tid < 32) {
        float s = 0.f;
#pragma unroll 8
        for (int k = 0; k < 64; ++k) s += qt[tid][k] * qt[tid][k];
        diag[tid] = 0.5f * s;
    }
    __syncthreads();

    for (int idx = tid; idx < 32 * Mm; idx += 256) {
        int n = idx & 31, m = idx >> 5;
        const float* pr = proj + m * DHh;
        float s = 0.f;
#pragma unroll 8
        for (int k = 0; k < 64; ++k) s += qt[n][k] * pr[k];
        qf[n][m] = s;
    }
    __syncthreads();

    const int r = tid & 31, g = tid >> 5;
    float mx = -3.0e38f;
    for (int m = g; m < Mm; m += 8) mx = fmaxf(mx, qf[r][m]);
    red[tid] = mx;
    __syncthreads();
    if (tid < 32) {
        float s = red[tid];
#pragma unroll
        for (int gg = 1; gg < 8; ++gg) s = fmaxf(s, red[gg * 32 + tid]);
        stab[tid] = s;
    }
    __syncthreads();

    float ds = 0.f;
    {
        float dg = diag[r], st = stab[r];
        for (int m = g; m < Mm; m += 8) {
            float val = RATIO * (__expf(qf[r][m] - dg - st) + EPS_FAVOR);
            qf[r][m] = val;
            ds += val * ksum[(size_t)bh * Mm + m];
        }
    }
    red[tid] = ds;
    __syncthreads();
    if (tid < 32) {
        float s = 0.f;
#pragma unroll
        for (int gg = 0; gg < 8; ++gg) s += red[gg * 32 + tid];
        dinv[tid] = 1.0f / s;
    }
    __syncthreads();

    const int tx = tid & 63, ty = tid >> 6;
    float acc8[8] = {};
    for (int m = 0; m < Mm; ++m) {
        float c = ctx[((size_t)bh * Mm + m) * DHh + tx];
#pragma unroll
        for (int t = 0; t < 8; ++t) acc8[t] += qf[ty * 8 + t][m] * c;
    }
#pragma unroll
    for (int t = 0; t < 8; ++t) {
        int n = ty * 8 + t;
        attnb[((size_t)(b * Nn + n0 + n)) * Dd + h * DHh + tx] = f2bf(acc8[t] * dinv[n]);
    }
}

// ---------------------------------------------------------------------------
// LayerNorm: one block per row of 1024
// ---------------------------------------------------------------------------
__global__ __launch_bounds__(256) void ln_kernel(
    const float* __restrict__ y, const float* __restrict__ gamma,
    const float* __restrict__ beta, float* __restrict__ out)
{
    const int row = blockIdx.x;
    const int tid = threadIdx.x;
    float4 v = *(const float4*)(y + (size_t)row * Dd + tid * 4);
    float s = v.x + v.y + v.z + v.w;
    float q = v.x * v.x + v.y * v.y + v.z * v.z + v.w * v.w;
    __shared__ float rs[256], rq[256];
    rs[tid] = s; rq[tid] = q;
    __syncthreads();
    for (int off = 128; off > 0; off >>= 1) {
        if (tid < off) { rs[tid] += rs[tid + off]; rq[tid] += rq[tid + off]; }
        __syncthreads();
    }
    float mu = rs[0] * (1.0f / Dd);
    float var = rq[0] * (1.0f / Dd) - mu * mu;
    float rstd = rsqrtf(var + EPS_LN);
    float4 gm = *(const float4*)(gamma + tid * 4);
    float4 bt = *(const float4*)(beta + tid * 4);
    float4 o;
    o.x = (v.x - mu) * rstd * gm.x + bt.x;
    o.y = (v.y - mu) * rstd * gm.y + bt.y;
    o.z = (v.z - mu) * rstd * gm.z + bt.z;
    o.w = (v.w - mu) * rstd * gm.w + bt.w;
    *(float4*)(out + (size_t)row * Dd + tid * 4) = o;
}

// ---------------------------------------------------------------------------
extern "C" void kernel_launch(void* const* d_in, const int* in_sizes, int n_in,
                              void* d_out, int out_size, void* d_ws, size_t ws_size,
                              hipStream_t stream) {
    const float* x     = (const float*)d_in[0];
    const float* Wq    = (const float*)d_in[1];
    const float* Wk    = (const float*)d_in[2];
    const float* Wv    = (const float*)d_in[3];
    const float* Wo    = (const float*)d_in[4];
    const float* bo    = (const float*)d_in[5];
    const float* proj  = (const float*)d_in[6];
    const float* gamma = (const float*)d_in[7];
    const float* beta  = (const float*)d_in[8];
    float* out = (float*)d_out;

    const size_t TS = 16777216;           // tokens(16384) * 1024
    ushort* xb  = (ushort*)d_ws;          // x bf16; reused as vbT then attnb
    ushort* qb  = xb + TS;
    ushort* kb  = qb + TS;
    ushort* vb  = kb + TS;
    ushort* WTq = vb + TS;
    ushort* WTk = WTq + 1048576;
    ushort* WTv = WTk + 1048576;
    ushort* WTo = WTv + 1048576;
    float*  ctx  = (float*)(WTo + 1048576);         // BH*M*64 fp32
    float*  ksum = ctx + (size_t)BHh * Mm * DHh;    // BH*M
    unsigned* stab = (unsigned*)(ksum + (size_t)BHh * Mm);
    ushort* attnb = xb;                   // token-major bf16 attn
    float*  yres  = (float*)qb;           // fp32, overlays qb+kb after qout
    // overlays valid once the QKV GEMM has consumed xb / WTq / WTk:
    ushort* vbT    = xb;                  // [bh][64][4096] bf16 = exactly TS ushorts
    float*  diagk  = (float*)WTq;         // 1 MB in the 2 MB WTq slot
    ushort* projb2 = WTk;                 // 80 KB in the 2 MB WTk slot

    hipMemsetAsync(ctx, 0, (size_t)BHh * Mm * DHh * sizeof(float), stream);
    hipMemsetAsync(ksum, 0, (size_t)BHh * Mm * sizeof(float), stream);
    hipMemsetAsync(stab, 0, BHh * sizeof(unsigned), stream);

    conv_x_kernel<<<8192, 256, 0, stream>>>(x, xb);
    conv_wt_kernel<<<dim3(16, 16, 4), 256, 0, stream>>>(Wq, Wk, Wv, Wo, WTq, WTk, WTv, WTo);

    gemm_bt<<<dim3(128, 8, 3), 256, 0, stream>>>(xb, WTq, WTk, WTv, qb, kb, vb,
                                                 nullptr, nullptr, nullptr, 0);

    // prep for MFMA ctx (all depend only on qkv-gemm outputs / raw inputs)
    diag_kernel<<<1024, 256, 0, stream>>>(kb, diagk);
    conv_proj_kernel<<<80, 256, 0, stream>>>(proj, projb2);
    transpose_v_kernel<<<dim3(64, 64), 256, 0, stream>>>(vb, vbT);

    kstab_kernel<<<dim3(BHh, Nn / 64), 256, 0, stream>>>(kb, proj, stab);

    ctx_mfma_kernel<<<dim3(5, 4, BHh), 256, 0, stream>>>(kb, vbT, projb2, diagk, stab,
                                                         ctx, ksum);

    qout_kernel<<<dim3(Nn / 32, BHh), 256, 0, stream>>>(qb, proj, ctx, ksum, attnb);

    gemm_bt<<<dim3(128, 8, 1), 256, 0, stream>>>(attnb, WTo, nullptr, nullptr,
                                                 nullptr, nullptr, nullptr, bo, x, yres, 1);
    ln_kernel<<<16384, 256, 0, stream>>>(yres, gamma, beta, out);
}

// Round 2
// 750.909 us; speedup vs baseline: 7.2998x; 2.2333x over previous
//
#include <hip/hip_runtime.h>
#include <hip/hip_bf16.h>
#include <math.h>

// Problem constants
#define Bb 4
#define Nn 4096
#define Hh 16
#define DHh 64
#define Mm 266
#define Dd 1024
#define BHh (Bb*Hh)

#define DN_SCALE 0.35355339059327373f   // 64^-0.25
#define RATIO 0.06131393394849658f      // 266^-0.5
#define EPS_FAVOR 1e-4f
#define EPS_LN 1e-5f

typedef __attribute__((ext_vector_type(8))) short frag_t;   // 8 x bf16
typedef __attribute__((ext_vector_type(4))) short sh4;      // 4 x bf16
typedef __attribute__((ext_vector_type(4))) float f32x4;

__device__ __forceinline__ ushort f2bf(float f) {
    unsigned u = __float_as_uint(f);
    return (ushort)((u + 0x7FFFu + ((u >> 16) & 1u)) >> 16);
}
__device__ __forceinline__ float bf2f(ushort h) {
    return __uint_as_float(((unsigned)h) << 16);
}
__device__ __forceinline__ unsigned fenc(float f) {
    unsigned u = __float_as_uint(f);
    return (u & 0x80000000u) ? ~u : (u | 0x80000000u);
}
__device__ __forceinline__ float fdec(unsigned e) {
    unsigned u = (e & 0x80000000u) ? (e ^ 0x80000000u) : ~e;
    return __uint_as_float(u);
}
__device__ __forceinline__ void gld16(const void* g, void* l) {
    __builtin_amdgcn_global_load_lds((const __attribute__((address_space(1))) unsigned int*)g,
                                     (__attribute__((address_space(3))) unsigned int*)l, 16, 0, 0);
}

// ---------------------------------------------------------------------------
// prep: x fp32 -> bf16
// ---------------------------------------------------------------------------
__global__ __launch_bounds__(256) void conv_x_kernel(const float* __restrict__ x,
                                                     ushort* __restrict__ xb) {
    size_t i = ((size_t)blockIdx.x * 256 + threadIdx.x) * 8;
    float4 f0 = *(const float4*)(x + i);
    float4 f1 = *(const float4*)(x + i + 4);
    uint4 o;
    o.x = (unsigned)f2bf(f0.x) | ((unsigned)f2bf(f0.y) << 16);
    o.y = (unsigned)f2bf(f0.z) | ((unsigned)f2bf(f0.w) << 16);
    o.z = (unsigned)f2bf(f1.x) | ((unsigned)f2bf(f1.y) << 16);
    o.w = (unsigned)f2bf(f1.z) | ((unsigned)f2bf(f1.w) << 16);
    *(uint4*)(xb + i) = o;
}

// prep: W[k][n] fp32 -> WT[n][k] bf16 (K-contiguous for the B^T GEMM)
__global__ __launch_bounds__(256) void conv_wt_kernel(
    const float* __restrict__ Wq, const float* __restrict__ Wk,
    const float* __restrict__ Wv, const float* __restrict__ Wo,
    ushort* __restrict__ Tq, ushort* __restrict__ Tk,
    ushort* __restrict__ Tv, ushort* __restrict__ To) {
    const int z = blockIdx.z;
    const float* W = z == 0 ? Wq : z == 1 ? Wk : z == 2 ? Wv : Wo;
    ushort* WT = z == 0 ? Tq : z == 1 ? Tk : z == 2 ? Tv : To;
    __shared__ float tls[64][65];
    const int tid = threadIdx.x;
    const int n0 = blockIdx.x * 64, k0 = blockIdx.y * 64;
    const int r = tid >> 2, seg = tid & 3;
#pragma unroll
    for (int i = 0; i < 4; ++i) {
        float4 f = *(const float4*)(W + (size_t)(k0 + r) * 1024 + n0 + seg * 16 + i * 4);
        tls[r][seg * 16 + i * 4 + 0] = f.x;
        tls[r][seg * 16 + i * 4 + 1] = f.y;
        tls[r][seg * 16 + i * 4 + 2] = f.z;
        tls[r][seg * 16 + i * 4 + 3] = f.w;
    }
    __syncthreads();
    const int nl = tid >> 2;
#pragma unroll
    for (int i = 0; i < 16; ++i)
        WT[(size_t)(n0 + nl) * 1024 + k0 + seg * 16 + i] = f2bf(tls[seg * 16 + i][nl]);
}

// prep: proj fp32 [266][64] -> bf16 hi/lo [320][128], zero-padded rows
__global__ __launch_bounds__(256) void conv_proj_kernel(const float* __restrict__ proj,
                                                        ushort* __restrict__ pb) {
    const int idx = blockIdx.x * 256 + threadIdx.x;   // 320*64 = 20480
    const int m = idx >> 6, k = idx & 63;
    float v = (m < Mm) ? proj[m * 64 + k] : 0.f;
    ushort hi = f2bf(v);
    float lo = v - bf2f(hi);
    pb[m * 128 + k] = hi;
    pb[m * 128 + 64 + k] = f2bf(lo);
}

// prep: v head-major [bh][n][64] -> vT [bh][64][4096] bf16
__global__ __launch_bounds__(256) void transpose_v_kernel(const ushort* __restrict__ vv,
                                                          ushort* __restrict__ vT) {
    const int bh = blockIdx.y;
    const int n0 = blockIdx.x * 64;
    __shared__ ushort tls[64 * 72];
    const int tid = threadIdx.x;
    const int r = tid >> 2, s = tid & 3;
    *(frag_t*)&tls[r * 72 + s * 16] =
        *(const frag_t*)(vv + ((size_t)bh * Nn + n0 + r) * 64 + s * 16);
    *(frag_t*)&tls[r * 72 + s * 16 + 8] =
        *(const frag_t*)(vv + ((size_t)bh * Nn + n0 + r) * 64 + s * 16 + 8);
    __syncthreads();
    const int d = tid >> 2, s2 = tid & 3;
    frag_t o0, o1;
#pragma unroll
    for (int i = 0; i < 8; ++i) o0[i] = (short)tls[(s2 * 16 + i) * 72 + d];
#pragma unroll
    for (int i = 0; i < 8; ++i) o1[i] = (short)tls[(s2 * 16 + 8 + i) * 72 + d];
    *(frag_t*)(vT + ((size_t)bh * 64 + d) * Nn + n0 + s2 * 16) = o0;
    *(frag_t*)(vT + ((size_t)bh * 64 + d) * Nn + n0 + s2 * 16 + 8) = o1;
}

// prep: diag[bh*4096+n] = 0.5 * sum_k kb[n][k]^2
__global__ __launch_bounds__(256) void diag_kernel(const ushort* __restrict__ kb,
                                                   float* __restrict__ dg) {
    const size_t i = (size_t)blockIdx.x * 256 + threadIdx.x;
    const ushort* p = kb + i * 64;
    float s = 0.f;
#pragma unroll
    for (int seg = 0; seg < 8; ++seg) {
        frag_t a = *(const frag_t*)(p + seg * 8);
#pragma unroll
        for (int j = 0; j < 8; ++j) { float f = bf2f((ushort)a[j]); s += f * f; }
    }
    dg[i] = 0.5f * s;
}

// prep: ctx fp32 [bh][m][64] -> ctxT hi/lo bf16 [bh][64 d][320 hi | 320 lo]
__global__ __launch_bounds__(256) void ctx2bt_kernel(const float* __restrict__ ctx,
                                                     ushort* __restrict__ cT) {
    const int mc = blockIdx.x;       // 0..4
    const int bh = blockIdx.y;
    const int tid = threadIdx.x;
    __shared__ float tls[64][65];
    const int r = tid >> 2, cs = tid & 3;
    const int gm = mc * 64 + r;
#pragma unroll
    for (int i = 0; i < 4; ++i) {
        float4 f = {0.f, 0.f, 0.f, 0.f};
        if (gm < Mm) f = *(const float4*)(ctx + ((size_t)bh * Mm + gm) * 64 + cs * 16 + i * 4);
        tls[r][cs * 16 + i * 4 + 0] = f.x;
        tls[r][cs * 16 + i * 4 + 1] = f.y;
        tls[r][cs * 16 + i * 4 + 2] = f.z;
        tls[r][cs * 16 + i * 4 + 3] = f.w;
    }
    __syncthreads();
    const int d = tid >> 2, ms = tid & 3;
    unsigned hi[8], lo[8];
#pragma unroll
    for (int j = 0; j < 8; ++j) {
        float v0 = tls[ms * 16 + j * 2][d];
        float v1 = tls[ms * 16 + j * 2 + 1][d];
        ushort h0 = f2bf(v0), h1 = f2bf(v1);
        ushort l0 = f2bf(v0 - bf2f(h0)), l1 = f2bf(v1 - bf2f(h1));
        hi[j] = (unsigned)h0 | ((unsigned)h1 << 16);
        lo[j] = (unsigned)l0 | ((unsigned)l1 << 16);
    }
    size_t base = (size_t)bh * 40960 + (size_t)d * 640 + mc * 64 + ms * 16;
    uint4 a = {hi[0], hi[1], hi[2], hi[3]};
    uint4 b = {hi[4], hi[5], hi[6], hi[7]};
    uint4 c = {lo[0], lo[1], lo[2], lo[3]};
    uint4 e = {lo[4], lo[5], lo[6], lo[7]};
    *(uint4*)(cT + base) = a;
    *(uint4*)(cT + base + 8) = b;
    *(uint4*)(cT + base + 320) = c;
    *(uint4*)(cT + base + 328) = e;
}

// ---------------------------------------------------------------------------
// bf16 MFMA GEMM (m97 pattern): C[16384,1024] = A @ WT^T
// mode 0: head-major bf16 out (z selects W/out/scale)  mode 1: fp32 +bias+resid
// ---------------------------------------------------------------------------
__global__ __launch_bounds__(256) void gemm_bt(
    const ushort* __restrict__ A,
    const ushort* __restrict__ W0, const ushort* __restrict__ W1, const ushort* __restrict__ W2,
    ushort* __restrict__ o0, ushort* __restrict__ o1, ushort* __restrict__ o2,
    const float* __restrict__ bo, const float* __restrict__ xres, float* __restrict__ yres,
    int mode)
{
    __shared__ ushort As[128 * 32];
    __shared__ ushort Bs[128 * 32];
    const int tid = threadIdx.x;
    const int lane = tid & 63, w = tid >> 6;
    const int q = lane >> 4, m16 = lane & 15;
    const int wm = w & 1, wn = w >> 1;
    const int by = blockIdx.x, bx = blockIdx.y, z = blockIdx.z;
    const int row0 = by * 128, col0 = bx * 128;
    const ushort* WT = (mode == 0) ? (z == 0 ? W0 : z == 1 ? W1 : W2) : W0;

    f32x4 acc[4][4];
#pragma unroll
    for (int i = 0; i < 4; ++i)
#pragma unroll
        for (int j = 0; j < 4; ++j) acc[i][j] = (f32x4){0.f, 0.f, 0.f, 0.f};

    const int srow = lane >> 2;
    const int sseg = lane & 3;
    const int c0i = w * 2;

    for (int k0 = 0; k0 < 1024; k0 += 32) {
        __syncthreads();
#pragma unroll
        for (int c = 0; c < 2; ++c) {
            int idx = c0i + c;
            int ra = idx * 16 + srow;
            gld16(A  + (size_t)(row0 + ra) * 1024 + k0 + sseg * 8, (void*)(As + idx * 512 + lane * 8));
            gld16(WT + (size_t)(col0 + ra) * 1024 + k0 + sseg * 8, (void*)(Bs + idx * 512 + lane * 8));
        }
        __syncthreads();
        frag_t af[4], bf[4];
#pragma unroll
        for (int t = 0; t < 4; ++t) {
            af[t] = *(const frag_t*)&As[(wm * 64 + t * 16 + m16) * 32 + q * 8];
            bf[t] = *(const frag_t*)&Bs[(wn * 64 + t * 16 + m16) * 32 + q * 8];
        }
#pragma unroll
        for (int i = 0; i < 4; ++i)
#pragma unroll
            for (int j = 0; j < 4; ++j)
                acc[i][j] = __builtin_amdgcn_mfma_f32_16x16x32_bf16(af[i], bf[j], acc[i][j], 0, 0, 0);
    }

    if (mode == 0) {
        const float scale = (z < 2) ? DN_SCALE : 1.0f;
        ushort* outp = z == 0 ? o0 : z == 1 ? o1 : o2;
#pragma unroll
        for (int i = 0; i < 4; ++i)
#pragma unroll
            for (int j = 0; j < 4; ++j)
#pragma unroll
                for (int r = 0; r < 4; ++r) {
                    int row = row0 + wm * 64 + i * 16 + q * 4 + r;
                    int col = col0 + wn * 64 + j * 16 + m16;
                    int b = row >> 12, n = row & 4095;
                    int h = col >> 6, dh = col & 63;
                    outp[((size_t)((b << 4) + h) * 4096 + n) * 64 + dh] = f2bf(acc[i][j][r] * scale);
                }
    } else {
#pragma unroll
        for (int i = 0; i < 4; ++i)
#pragma unroll
            for (int j = 0; j < 4; ++j)
#pragma unroll
                for (int r = 0; r < 4; ++r) {
                    int row = row0 + wm * 64 + i * 16 + q * 4 + r;
                    int col = col0 + wn * 64 + j * 16 + m16;
                    size_t off = (size_t)row * 1024 + col;
                    yres[off] = acc[i][j][r] + bo[col] + xres[off];
                }
    }
}

// ---------------------------------------------------------------------------
// k-stab via MFMA: per block 64 n-rows, full 320 m; max-reduce -> atomicMax
// grid: (Nn/64, BH), block 256 (4 waves x 16 rows)
// ---------------------------------------------------------------------------
__global__ __launch_bounds__(256) void kstab_mfma_kernel(
    const ushort* __restrict__ kb, const ushort* __restrict__ pb,
    unsigned* __restrict__ stab_enc)
{
    const int n0 = blockIdx.x * 64;
    const int bh = blockIdx.y;
    const int tid = threadIdx.x;
    const int lane = tid & 63, w = tid >> 6;
    const int q = lane >> 4, m16 = lane & 15;

    __shared__ ushort ks_s[64 * 72];
    __shared__ ushort pj_s[64 * 136];

#pragma unroll
    for (int t = 0; t < 2; ++t) {
        int idx = tid + t * 256;
        int r = idx >> 3, s = idx & 7;
        *(frag_t*)&ks_s[r * 72 + s * 8] =
            *(const frag_t*)(kb + ((size_t)bh * Nn + n0 + r) * 64 + s * 8);
    }
    __syncthreads();

    frag_t aq[2];
#pragma unroll
    for (int s = 0; s < 2; ++s)
        aq[s] = *(const frag_t*)&ks_s[(w * 16 + m16) * 72 + s * 32 + q * 8];

    float mx = -3.0e38f;
#pragma unroll
    for (int mc = 0; mc < 5; ++mc) {
        __syncthreads();
#pragma unroll
        for (int t = 0; t < 4; ++t) {
            int idx = tid + t * 256;
            int r = idx >> 4, c = idx & 15;
            *(frag_t*)&pj_s[r * 136 + c * 8] =
                *(const frag_t*)(pb + ((size_t)mc * 64 + r) * 128 + c * 8);
        }
        __syncthreads();
#pragma unroll
        for (int tm = 0; tm < 4; ++tm) {
            const int t = mc * 4 + tm;
            if (t > 16) continue;          // fully out of range
            f32x4 sa = (f32x4){0.f, 0.f, 0.f, 0.f};
#pragma unroll
            for (int s = 0; s < 2; ++s) {
                const ushort* pr = &pj_s[(tm * 16 + m16) * 136 + s * 32 + q * 8];
                frag_t bhi = *(const frag_t*)pr;
                frag_t blo = *(const frag_t*)(pr + 64);
                sa = __builtin_amdgcn_mfma_f32_16x16x32_bf16(aq[s], bhi, sa, 0, 0, 0);
                sa = __builtin_amdgcn_mfma_f32_16x16x32_bf16(aq[s], blo, sa, 0, 0, 0);
            }
            bool v = (t < 16) || (m16 < 10);
            if (v) {
#pragma unroll
                for (int r = 0; r < 4; ++r) mx = fmaxf(mx, sa[r]);
            }
        }
    }
    // full-wave max
    mx = fmaxf(mx, __shfl_xor(mx, 1));
    mx = fmaxf(mx, __shfl_xor(mx, 2));
    mx = fmaxf(mx, __shfl_xor(mx, 4));
    mx = fmaxf(mx, __shfl_xor(mx, 8));
    mx = fmaxf(mx, __shfl_xor(mx, 16));
    mx = fmaxf(mx, __shfl_xor(mx, 32));
    if (lane == 0) atomicMax(stab_enc + bh, fenc(mx));
}

// ---------------------------------------------------------------------------
// ctx via MFMA (unchanged from R1)
// ---------------------------------------------------------------------------
__global__ __launch_bounds__(256) void ctx_mfma_kernel(
    const ushort* __restrict__ kb, const ushort* __restrict__ vT,
    const ushort* __restrict__ pb, const float* __restrict__ diagk,
    const unsigned* __restrict__ stab_enc,
    float* __restrict__ ctx, float* __restrict__ ksum)
{
    const int m0 = blockIdx.x * 64;
    const int nb = blockIdx.y;
    const int bh = blockIdx.z;
    const int tid = threadIdx.x;
    const int lane = tid & 63, w = tid >> 6;
    const int q = lane >> 4, m16 = lane & 15;
    const float kst = fdec(stab_enc[bh]);

    __shared__ ushort ks_s[32 * 72];
    __shared__ ushort pj_s[64 * 136];
    __shared__ ushort kf_s[64 * 40];
    __shared__ ushort vt_s[64 * 40];
    __shared__ float  diag_s[32];

    for (int u = tid; u < 1024; u += 256) {
        int r = u >> 4, c = (u & 15) * 8;
        *(frag_t*)&pj_s[r * 136 + c] = *(const frag_t*)(pb + (size_t)(m0 + r) * 128 + c);
    }

    f32x4 acc_c[4];
#pragma unroll
    for (int j = 0; j < 4; ++j) acc_c[j] = (f32x4){0.f, 0.f, 0.f, 0.f};
    float ksacc[2] = {0.f, 0.f};

    const int tn  = w & 1;
    const int tmb = (w >> 1) * 2;

    const int srow_k = tid >> 3, sseg_k = tid & 7;
    const int srow_v = tid >> 2, sseg_v = tid & 3;
    const size_t kbase = ((size_t)bh * Nn + nb * 1024 + srow_k) * 64 + sseg_k * 8;
    const size_t vbase = ((size_t)bh * 64 + srow_v) * Nn + nb * 1024 + sseg_v * 8;
    const float* dgp = diagk + (size_t)bh * Nn + nb * 1024;

    frag_t kreg = *(const frag_t*)(kb + kbase);
    frag_t vreg = *(const frag_t*)(vT + vbase);
    float4 dreg;
    if (tid < 8) dreg = *(const float4*)(dgp + tid * 4);

    for (int t = 0; t < 32; ++t) {
        __syncthreads();
        *(frag_t*)&ks_s[srow_k * 72 + sseg_k * 8] = kreg;
        *(frag_t*)&vt_s[srow_v * 40 + sseg_v * 8] = vreg;
        if (tid < 8) *(float4*)&diag_s[tid * 4] = dreg;
        __syncthreads();
        if (t < 31) {
            kreg = *(const frag_t*)(kb + kbase + (size_t)(t + 1) * 2048);
            vreg = *(const frag_t*)(vT + vbase + (size_t)(t + 1) * 32);
            if (tid < 8) dreg = *(const float4*)(dgp + (t + 1) * 32 + tid * 4);
        }

        f32x4 sa[2];
        sa[0] = (f32x4){0.f, 0.f, 0.f, 0.f};
        sa[1] = (f32x4){0.f, 0.f, 0.f, 0.f};
#pragma unroll
        for (int s = 0; s < 2; ++s) {
            frag_t a = *(const frag_t*)&ks_s[(tn * 16 + m16) * 72 + s * 32 + q * 8];
#pragma unroll
            for (int jj = 0; jj < 2; ++jj) {
                const ushort* prow = &pj_s[((tmb + jj) * 16 + m16) * 136 + s * 32 + q * 8];
                frag_t bhi = *(const frag_t*)prow;
                frag_t blo = *(const frag_t*)(prow + 64);
                sa[jj] = __builtin_amdgcn_mfma_f32_16x16x32_bf16(a, bhi, sa[jj], 0, 0, 0);
                sa[jj] = __builtin_amdgcn_mfma_f32_16x16x32_bf16(a, blo, sa[jj], 0, 0, 0);
            }
        }

#pragma unroll
        for (int jj = 0; jj < 2; ++jj) {
            int m_l = (tmb + jj) * 16 + m16;
            bool valid = (m0 + m_l) < Mm;
            sh4 pk;
            float vsum = 0.f;
#pragma unroll
            for (int r = 0; r < 4; ++r) {
                int n_l = tn * 16 + q * 4 + r;
                float val = valid ? RATIO * (__expf(sa[jj][r] - diag_s[n_l] - kst) + EPS_FAVOR) : 0.f;
                ushort hb = f2bf(val);
                pk[r] = (short)hb;
                vsum += bf2f(hb);
            }
            ksacc[jj] += vsum;
            *(sh4*)&kf_s[m_l * 40 + tn * 16 + q * 4] = pk;
        }
        __syncthreads();

        {
            frag_t a = *(const frag_t*)&kf_s[(w * 16 + m16) * 40 + q * 8];
#pragma unroll
            for (int j = 0; j < 4; ++j) {
                frag_t b = *(const frag_t*)&vt_s[(j * 16 + m16) * 40 + q * 8];
                acc_c[j] = __builtin_amdgcn_mfma_f32_16x16x32_bf16(a, b, acc_c[j], 0, 0, 0);
            }
        }
    }

#pragma unroll
    for (int j = 0; j < 4; ++j)
#pragma unroll
        for (int r = 0; r < 4; ++r) {
            int m = m0 + w * 16 + q * 4 + r;
            if (m < Mm)
                atomicAdd(&ctx[((size_t)bh * Mm + m) * 64 + j * 16 + m16], acc_c[j][r]);
        }
#pragma unroll
    for (int jj = 0; jj < 2; ++jj) {
        float v = ksacc[jj];
        v += __shfl_xor(v, 16);
        v += __shfl_xor(v, 32);
        int m = m0 + (tmb + jj) * 16 + m16;
        if (q == 0 && m < Mm) atomicAdd(&ksum[(size_t)bh * Mm + m], v);
    }
}

// ---------------------------------------------------------------------------
// q-side via MFMA: 64 rows/block, 4 waves x 16 rows.
//   feature GEMM S[16n][320m] in regs (hi/lo proj) -> row stats via shfl ->
//   qf bf16 -> LDS -> PV GEMM vs ctxT hi/lo -> *dinv -> attnb
// grid: (Nn/64, BH), block 256
// ---------------------------------------------------------------------------
__global__ __launch_bounds__(256) void qout_mfma_kernel(
    const ushort* __restrict__ qb, const ushort* __restrict__ pb,
    const ushort* __restrict__ cT, const float* __restrict__ ksum,
    ushort* __restrict__ attnb)
{
    const int n0 = blockIdx.x * 64;
    const int bh = blockIdx.y;
    const int b = bh >> 4, h = bh & 15;
    const int tid = threadIdx.x;
    const int lane = tid & 63, w = tid >> 6;
    const int q = lane >> 4, m16 = lane & 15;

    __shared__ ushort qs_s[64 * 72];
    __shared__ ushort pj_s[64 * 136];
    __shared__ ushort qf_s[64 * 328];
    __shared__ float  diag_s[64];
    __shared__ float  ksum_s[320];

    // stage Q tile + ksum
#pragma unroll
    for (int t = 0; t < 2; ++t) {
        int idx = tid + t * 256;
        int r = idx >> 3, s = idx & 7;
        *(frag_t*)&qs_s[r * 72 + s * 8] =
            *(const frag_t*)(qb + ((size_t)bh * Nn + n0 + r) * 64 + s * 8);
    }
    for (int m = tid; m < 320; m += 256)
        ksum_s[m] = (m < Mm) ? ksum[(size_t)bh * Mm + m] : 0.f;
    __syncthreads();
    if (tid < 64) {
        float s = 0.f;
#pragma unroll 8
        for (int k = 0; k < 64; ++k) { float f = bf2f(qs_s[tid * 72 + k]); s += f * f; }
        diag_s[tid] = 0.5f * s;
    }

    frag_t aq[2];
#pragma unroll
    for (int s = 0; s < 2; ++s)
        aq[s] = *(const frag_t*)&qs_s[(w * 16 + m16) * 72 + s * 32 + q * 8];

    // ---- feature GEMM: S[16 rows][320 m] in registers ----
    f32x4 sA[20];
#pragma unroll
    for (int t = 0; t < 20; ++t) sA[t] = (f32x4){0.f, 0.f, 0.f, 0.f};

#pragma unroll
    for (int mc = 0; mc < 5; ++mc) {
        __syncthreads();
#pragma unroll
        for (int t = 0; t < 4; ++t) {
            int idx = tid + t * 256;
            int r = idx >> 4, c = idx & 15;
            *(frag_t*)&pj_s[r * 136 + c * 8] =
                *(const frag_t*)(pb + ((size_t)mc * 64 + r) * 128 + c * 8);
        }
        __syncthreads();
#pragma unroll
        for (int tm = 0; tm < 4; ++tm) {
#pragma unroll
            for (int s = 0; s < 2; ++s) {
                const ushort* pr = &pj_s[(tm * 16 + m16) * 136 + s * 32 + q * 8];
                frag_t bhi = *(const frag_t*)pr;
                frag_t blo = *(const frag_t*)(pr + 64);
                sA[mc * 4 + tm] = __builtin_amdgcn_mfma_f32_16x16x32_bf16(aq[s], bhi, sA[mc * 4 + tm], 0, 0, 0);
                sA[mc * 4 + tm] = __builtin_amdgcn_mfma_f32_16x16x32_bf16(aq[s], blo, sA[mc * 4 + tm], 0, 0, 0);
            }
        }
    }

    // ---- row stats: stab max over valid m (cols in 16-lane group) ----
    float mx[4] = {-3.0e38f, -3.0e38f, -3.0e38f, -3.0e38f};
#pragma unroll
    for (int t = 0; t < 17; ++t) {
        bool v = (t < 16) || (m16 < 10);
        if (v) {
#pragma unroll
            for (int r = 0; r < 4; ++r) mx[r] = fmaxf(mx[r], sA[t][r]);
        }
    }
#pragma unroll
    for (int r = 0; r < 4; ++r) {
        float v = mx[r];
        v = fmaxf(v, __shfl_xor(v, 1));
        v = fmaxf(v, __shfl_xor(v, 2));
        v = fmaxf(v, __shfl_xor(v, 4));
        v = fmaxf(v, __shfl_xor(v, 8));
        mx[r] = v;
    }
    float dg[4];
#pragma unroll
    for (int r = 0; r < 4; ++r) dg[r] = diag_s[w * 16 + q * 4 + r];

    // ---- exp, ksum dot, qf -> LDS (bf16) ----
    float ds[4] = {0.f, 0.f, 0.f, 0.f};
#pragma unroll
    for (int t = 0; t < 20; ++t) {
        int m = t * 16 + m16;
        bool v = m < Mm;
        float ksm = ksum_s[m];
#pragma unroll
        for (int r = 0; r < 4; ++r) {
            ushort hb = 0;
            float val = 0.f;
            if (v) {
                hb = f2bf(RATIO * (__expf(sA[t][r] - dg[r] - mx[r]) + EPS_FAVOR));
                val = bf2f(hb);
            }
            ds[r] += val * ksm;
            qf_s[(w * 16 + q * 4 + r) * 328 + m] = hb;
        }
    }
#pragma unroll
    for (int r = 0; r < 4; ++r) {
        float v = ds[r];
        v += __shfl_xor(v, 1);
        v += __shfl_xor(v, 2);
        v += __shfl_xor(v, 4);
        v += __shfl_xor(v, 8);
        ds[r] = 1.0f / v;
    }

    // ---- PV GEMM: out[16 rows][64 d] = qf @ ctxT^T (hi+lo) ----
    f32x4 oA[4];
#pragma unroll
    for (int dt = 0; dt < 4; ++dt) oA[dt] = (f32x4){0.f, 0.f, 0.f, 0.f};

#pragma unroll
    for (int mc = 0; mc < 5; ++mc) {
        __syncthreads();
#pragma unroll
        for (int t = 0; t < 4; ++t) {
            int idx = tid + t * 256;
            int dd = idx >> 4, c = idx & 15;
            int off = (c >> 3) * 320 + mc * 64 + (c & 7) * 8;
            *(frag_t*)&pj_s[dd * 136 + c * 8] =
                *(const frag_t*)(cT + (size_t)bh * 40960 + (size_t)dd * 640 + off);
        }
        __syncthreads();
#pragma unroll
        for (int s = 0; s < 2; ++s) {
            frag_t a = *(const frag_t*)&qf_s[(w * 16 + m16) * 328 + mc * 64 + s * 32 + q * 8];
#pragma unroll
            for (int dt = 0; dt < 4; ++dt) {
                const ushort* pr = &pj_s[(dt * 16 + m16) * 136 + s * 32 + q * 8];
                frag_t bhi = *(const frag_t*)pr;
                frag_t blo = *(const frag_t*)(pr + 64);
                oA[dt] = __builtin_amdgcn_mfma_f32_16x16x32_bf16(a, bhi, oA[dt], 0, 0, 0);
                oA[dt] = __builtin_amdgcn_mfma_f32_16x16x32_bf16(a, blo, oA[dt], 0, 0, 0);
            }
        }
    }

    // ---- epilogue: * dinv, store bf16 ----
#pragma unroll
    for (int dt = 0; dt < 4; ++dt)
#pragma unroll
        for (int r = 0; r < 4; ++r) {
            int n = n0 + w * 16 + q * 4 + r;
            attnb[((size_t)(b * Nn + n)) * Dd + h * 64 + dt * 16 + m16] =
                f2bf(oA[dt][r] * ds[r]);
        }
}

// ---------------------------------------------------------------------------
// LayerNorm: one block per row of 1024
// ---------------------------------------------------------------------------
__global__ __launch_bounds__(256) void ln_kernel(
    const float* __restrict__ y, const float* __restrict__ gamma,
    const float* __restrict__ beta, float* __restrict__ out)
{
    const int row = blockIdx.x;
    const int tid = threadIdx.x;
    float4 v = *(const float4*)(y + (size_t)row * Dd + tid * 4);
    float s = v.x + v.y + v.z + v.w;
    float q = v.x * v.x + v.y * v.y + v.z * v.z + v.w * v.w;
    __shared__ float rs[256], rq[256];
    rs[tid] = s; rq[tid] = q;
    __syncthreads();
    for (int off = 128; off > 0; off >>= 1) {
        if (tid < off) { rs[tid] += rs[tid + off]; rq[tid] += rq[tid + off]; }
        __syncthreads();
    }
    float mu = rs[0] * (1.0f / Dd);
    float var = rq[0] * (1.0f / Dd) - mu * mu;
    float rstd = rsqrtf(var + EPS_LN);
    float4 gm = *(const float4*)(gamma + tid * 4);
    float4 bt = *(const float4*)(beta + tid * 4);
    float4 o;
    o.x = (v.x - mu) * rstd * gm.x + bt.x;
    o.y = (v.y - mu) * rstd * gm.y + bt.y;
    o.z = (v.z - mu) * rstd * gm.z + bt.z;
    o.w = (v.w - mu) * rstd * gm.w + bt.w;
    *(float4*)(out + (size_t)row * Dd + tid * 4) = o;
}

// ---------------------------------------------------------------------------
extern "C" void kernel_launch(void* const* d_in, const int* in_sizes, int n_in,
                              void* d_out, int out_size, void* d_ws, size_t ws_size,
                              hipStream_t stream) {
    const float* x     = (const float*)d_in[0];
    const float* Wq    = (const float*)d_in[1];
    const float* Wk    = (const float*)d_in[2];
    const float* Wv    = (const float*)d_in[3];
    const float* Wo    = (const float*)d_in[4];
    const float* bo    = (const float*)d_in[5];
    const float* proj  = (const float*)d_in[6];
    const float* gamma = (const float*)d_in[7];
    const float* beta  = (const float*)d_in[8];
    float* out = (float*)d_out;

    const size_t TS = 16777216;           // tokens(16384) * 1024
    ushort* xb  = (ushort*)d_ws;          // x bf16; reused as vbT then attnb
    ushort* qb  = xb + TS;
    ushort* kb  = qb + TS;
    ushort* vb  = kb + TS;
    ushort* WTq = vb + TS;
    ushort* WTk = WTq + 1048576;
    ushort* WTv = WTk + 1048576;
    ushort* WTo = WTv + 1048576;
    float*  ctx  = (float*)(WTo + 1048576);         // BH*M*64 fp32
    float*  ksum = ctx + (size_t)BHh * Mm * DHh;    // BH*M
    unsigned* stab = (unsigned*)(ksum + (size_t)BHh * Mm);
    ushort* attnb = xb;                   // token-major bf16 attn
    float*  yres  = (float*)qb;           // fp32, overlays qb+kb after qout
    // overlays (valid once producer kernels have consumed the regions):
    ushort* vbT    = xb;                  // [bh][64][4096] bf16 (after transpose_v)
    float*  diagk  = (float*)WTq;         // 1 MB in the 2 MB WTq slot
    ushort* projb2 = WTk;                 // 80 KB in the 2 MB WTk slot
    ushort* ctxT   = vb;                  // [bh][64][640] bf16 hi|lo (5.25 MB, vb free)

    hipMemsetAsync(ctx, 0, (size_t)BHh * Mm * DHh * sizeof(float), stream);
    hipMemsetAsync(ksum, 0, (size_t)BHh * Mm * sizeof(float), stream);
    hipMemsetAsync(stab, 0, BHh * sizeof(unsigned), stream);

    conv_x_kernel<<<8192, 256, 0, stream>>>(x, xb);
    conv_wt_kernel<<<dim3(16, 16, 4), 256, 0, stream>>>(Wq, Wk, Wv, Wo, WTq, WTk, WTv, WTo);

    gemm_bt<<<dim3(128, 8, 3), 256, 0, stream>>>(xb, WTq, WTk, WTv, qb, kb, vb,
                                                 nullptr, nullptr, nullptr, 0);

    diag_kernel<<<1024, 256, 0, stream>>>(kb, diagk);
    conv_proj_kernel<<<80, 256, 0, stream>>>(proj, projb2);
    transpose_v_kernel<<<dim3(64, 64), 256, 0, stream>>>(vb, vbT);

    kstab_mfma_kernel<<<dim3(Nn / 64, BHh), 256, 0, stream>>>(kb, projb2, stab);

    ctx_mfma_kernel<<<dim3(5, 4, BHh), 256, 0, stream>>>(kb, vbT, projb2, diagk, stab,
                                                         ctx, ksum);

    ctx2bt_kernel<<<dim3(5, BHh), 256, 0, stream>>>(ctx, ctxT);

    qout_mfma_kernel<<<dim3(Nn / 64, BHh), 256, 0, stream>>>(qb, projb2, ctxT, ksum, attnb);

    gemm_bt<<<dim3(128, 8, 1), 256, 0, stream>>>(attnb, WTo, nullptr, nullptr,
                                                 nullptr, nullptr, nullptr, bo, x, yres, 1);
    ln_kernel<<<16384, 256, 0, stream>>>(yres, gamma, beta, out);
}

// Round 4
// 733.621 us; speedup vs baseline: 7.4719x; 1.0236x over previous
//
#include <hip/hip_runtime.h>
#include <hip/hip_bf16.h>
#include <math.h>

// Problem constants
#define Bb 4
#define Nn 4096
#define Hh 16
#define DHh 64
#define Mm 266
#define Dd 1024
#define BHh (Bb*Hh)

#define DN_SCALE 0.35355339059327373f   // 64^-0.25
#define RATIO 0.06131393394849658f      // 266^-0.5
#define EPS_FAVOR 1e-4f
#define EPS_LN 1e-5f

typedef __attribute__((ext_vector_type(8))) short frag_t;   // 8 x bf16
typedef __attribute__((ext_vector_type(4))) short sh4;      // 4 x bf16
typedef __attribute__((ext_vector_type(4))) float f32x4;

__device__ __forceinline__ ushort f2bf(float f) {
    unsigned u = __float_as_uint(f);
    return (ushort)((u + 0x7FFFu + ((u >> 16) & 1u)) >> 16);
}
__device__ __forceinline__ float bf2f(ushort h) {
    return __uint_as_float(((unsigned)h) << 16);
}
__device__ __forceinline__ unsigned fenc(float f) {
    unsigned u = __float_as_uint(f);
    return (u & 0x80000000u) ? ~u : (u | 0x80000000u);
}
__device__ __forceinline__ float fdec(unsigned e) {
    unsigned u = (e & 0x80000000u) ? (e ^ 0x80000000u) : ~e;
    return __uint_as_float(u);
}
__device__ __forceinline__ void gld16(const void* g, void* l) {
    __builtin_amdgcn_global_load_lds((const __attribute__((address_space(1))) unsigned int*)g,
                                     (__attribute__((address_space(3))) unsigned int*)l, 16, 0, 0);
}

// ---------------------------------------------------------------------------
// prep: x fp32 -> bf16
// ---------------------------------------------------------------------------
__global__ __launch_bounds__(256) void conv_x_kernel(const float* __restrict__ x,
                                                     ushort* __restrict__ xb) {
    size_t i = ((size_t)blockIdx.x * 256 + threadIdx.x) * 8;
    float4 f0 = *(const float4*)(x + i);
    float4 f1 = *(const float4*)(x + i + 4);
    uint4 o;
    o.x = (unsigned)f2bf(f0.x) | ((unsigned)f2bf(f0.y) << 16);
    o.y = (unsigned)f2bf(f0.z) | ((unsigned)f2bf(f0.w) << 16);
    o.z = (unsigned)f2bf(f1.x) | ((unsigned)f2bf(f1.y) << 16);
    o.w = (unsigned)f2bf(f1.z) | ((unsigned)f2bf(f1.w) << 16);
    *(uint4*)(xb + i) = o;
}

// prep: W[k][n] fp32 -> WT[n][k] bf16 (K-contiguous for the B^T GEMM)
__global__ __launch_bounds__(256) void conv_wt_kernel(
    const float* __restrict__ Wq, const float* __restrict__ Wk,
    const float* __restrict__ Wv, const float* __restrict__ Wo,
    ushort* __restrict__ Tq, ushort* __restrict__ Tk,
    ushort* __restrict__ Tv, ushort* __restrict__ To) {
    const int z = blockIdx.z;
    const float* W = z == 0 ? Wq : z == 1 ? Wk : z == 2 ? Wv : Wo;
    ushort* WT = z == 0 ? Tq : z == 1 ? Tk : z == 2 ? Tv : To;
    __shared__ float tls[64][65];
    const int tid = threadIdx.x;
    const int n0 = blockIdx.x * 64, k0 = blockIdx.y * 64;
    const int r = tid >> 2, seg = tid & 3;
#pragma unroll
    for (int i = 0; i < 4; ++i) {
        float4 f = *(const float4*)(W + (size_t)(k0 + r) * 1024 + n0 + seg * 16 + i * 4);
        tls[r][seg * 16 + i * 4 + 0] = f.x;
        tls[r][seg * 16 + i * 4 + 1] = f.y;
        tls[r][seg * 16 + i * 4 + 2] = f.z;
        tls[r][seg * 16 + i * 4 + 3] = f.w;
    }
    __syncthreads();
    const int nl = tid >> 2;
#pragma unroll
    for (int i = 0; i < 16; ++i)
        WT[(size_t)(n0 + nl) * 1024 + k0 + seg * 16 + i] = f2bf(tls[seg * 16 + i][nl]);
}

// prep: proj fp32 [266][64] -> bf16 hi/lo [320][128], zero-padded rows
__global__ __launch_bounds__(256) void conv_proj_kernel(const float* __restrict__ proj,
                                                        ushort* __restrict__ pb) {
    const int idx = blockIdx.x * 256 + threadIdx.x;   // 320*64 = 20480
    const int m = idx >> 6, k = idx & 63;
    float v = (m < Mm) ? proj[m * 64 + k] : 0.f;
    ushort hi = f2bf(v);
    float lo = v - bf2f(hi);
    pb[m * 128 + k] = hi;
    pb[m * 128 + 64 + k] = f2bf(lo);
}

// prep: diag[bh*4096+n] = 0.5 * sum_k kb[n][k]^2
__global__ __launch_bounds__(256) void diag_kernel(const ushort* __restrict__ kb,
                                                   float* __restrict__ dg) {
    const size_t i = (size_t)blockIdx.x * 256 + threadIdx.x;
    const ushort* p = kb + i * 64;
    float s = 0.f;
#pragma unroll
    for (int seg = 0; seg < 8; ++seg) {
        frag_t a = *(const frag_t*)(p + seg * 8);
#pragma unroll
        for (int j = 0; j < 8; ++j) { float f = bf2f((ushort)a[j]); s += f * f; }
    }
    dg[i] = 0.5f * s;
}

// prep: ctx fp32 [bh][m][64] -> ctxT hi/lo bf16 [bh][64 d][320 hi | 320 lo]
__global__ __launch_bounds__(256) void ctx2bt_kernel(const float* __restrict__ ctx,
                                                     ushort* __restrict__ cT) {
    const int mc = blockIdx.x;       // 0..4
    const int bh = blockIdx.y;
    const int tid = threadIdx.x;
    __shared__ float tls[64][65];
    const int r = tid >> 2, cs = tid & 3;
    const int gm = mc * 64 + r;
#pragma unroll
    for (int i = 0; i < 4; ++i) {
        float4 f = {0.f, 0.f, 0.f, 0.f};
        if (gm < Mm) f = *(const float4*)(ctx + ((size_t)bh * Mm + gm) * 64 + cs * 16 + i * 4);
        tls[r][cs * 16 + i * 4 + 0] = f.x;
        tls[r][cs * 16 + i * 4 + 1] = f.y;
        tls[r][cs * 16 + i * 4 + 2] = f.z;
        tls[r][cs * 16 + i * 4 + 3] = f.w;
    }
    __syncthreads();
    const int d = tid >> 2, ms = tid & 3;
    unsigned hi[8], lo[8];
#pragma unroll
    for (int j = 0; j < 8; ++j) {
        float v0 = tls[ms * 16 + j * 2][d];
        float v1 = tls[ms * 16 + j * 2 + 1][d];
        ushort h0 = f2bf(v0), h1 = f2bf(v1);
        ushort l0 = f2bf(v0 - bf2f(h0)), l1 = f2bf(v1 - bf2f(h1));
        hi[j] = (unsigned)h0 | ((unsigned)h1 << 16);
        lo[j] = (unsigned)l0 | ((unsigned)l1 << 16);
    }
    size_t base = (size_t)bh * 40960 + (size_t)d * 640 + mc * 64 + ms * 16;
    uint4 a = {hi[0], hi[1], hi[2], hi[3]};
    uint4 b = {hi[4], hi[5], hi[6], hi[7]};
    uint4 c = {lo[0], lo[1], lo[2], lo[3]};
    uint4 e = {lo[4], lo[5], lo[6], lo[7]};
    *(uint4*)(cT + base) = a;
    *(uint4*)(cT + base + 8) = b;
    *(uint4*)(cT + base + 320) = c;
    *(uint4*)(cT + base + 328) = e;
}

// ---------------------------------------------------------------------------
// bf16 MFMA GEMM (m97 pattern + LDS XOR-swizzle): C[16384,1024] = A @ WT^T
// mode 0: head-major bf16 out via LDS-bounce coalesced stores (z 0,1) or
//         direct-transposed vT write (z==2).  mode 1: fp32 +bias+resid.
// ---------------------------------------------------------------------------
__global__ __launch_bounds__(256) void gemm_bt(
    const ushort* __restrict__ A,
    const ushort* __restrict__ W0, const ushort* __restrict__ W1, const ushort* __restrict__ W2,
    ushort* __restrict__ o0, ushort* __restrict__ o1, ushort* __restrict__ o2,
    const float* __restrict__ bo, const float* __restrict__ xres, float* __restrict__ yres,
    int mode)
{
    __shared__ ushort smem_s[8192];       // As [0,4096) | Bs [4096,8192); epilogue bounce
    ushort* As = smem_s;
    ushort* Bs = smem_s + 4096;
    const int tid = threadIdx.x;
    const int lane = tid & 63, w = tid >> 6;
    const int q = lane >> 4, m16 = lane & 15;
    const int wm = w & 1, wn = w >> 1;
    const int by = blockIdx.x, bx = blockIdx.y, z = blockIdx.z;
    const int row0 = by * 128, col0 = bx * 128;
    const ushort* WT = (mode == 0) ? (z == 0 ? W0 : z == 1 ? W1 : W2) : W0;

    f32x4 acc[4][4];
#pragma unroll
    for (int i = 0; i < 4; ++i)
#pragma unroll
        for (int j = 0; j < 4; ++j) acc[i][j] = (f32x4){0.f, 0.f, 0.f, 0.f};

    const int srow = lane >> 2;                          // row within 16-row chunk
    const int sseg = lane & 3;                           // k-segment (8 ushorts)
    const int ksw  = (sseg ^ ((srow >> 1) & 3)) * 8;     // pre-swizzled SOURCE k-offset
    const int c0i = w * 2;
    const int sq = (q ^ ((m16 >> 1) & 3)) * 8;           // swizzled READ k-offset

    for (int k0 = 0; k0 < 1024; k0 += 32) {
        __syncthreads();
#pragma unroll
        for (int c = 0; c < 2; ++c) {
            int idx = c0i + c;
            int ra = idx * 16 + srow;
            gld16(A  + (size_t)(row0 + ra) * 1024 + k0 + ksw, (void*)(As + idx * 512 + lane * 8));
            gld16(WT + (size_t)(col0 + ra) * 1024 + k0 + ksw, (void*)(Bs + idx * 512 + lane * 8));
        }
        __syncthreads();
        frag_t af[4], bf[4];
#pragma unroll
        for (int t = 0; t < 4; ++t) {
            af[t] = *(const frag_t*)&As[(wm * 64 + t * 16 + m16) * 32 + sq];
            bf[t] = *(const frag_t*)&Bs[(wn * 64 + t * 16 + m16) * 32 + sq];
        }
#pragma unroll
        for (int i = 0; i < 4; ++i)
#pragma unroll
            for (int j = 0; j < 4; ++j)
                acc[i][j] = __builtin_amdgcn_mfma_f32_16x16x32_bf16(af[i], bf[j], acc[i][j], 0, 0, 0);
    }

    if (mode == 0) {
        const int b = row0 >> 12;
        if (z == 2) {
            // direct transposed write: vT[((b*16+h)*64+dh)*4096 + n], 8B per lane
#pragma unroll
            for (int i = 0; i < 4; ++i)
#pragma unroll
                for (int j = 0; j < 4; ++j) {
                    int col = col0 + wn * 64 + j * 16 + m16;
                    size_t rowbase = ((size_t)((b << 4) + (col >> 6)) * 64 + (col & 63)) * 4096;
                    int n = (row0 & 4095) + wm * 64 + i * 16 + q * 4;
                    sh4 pk;
#pragma unroll
                    for (int r = 0; r < 4; ++r) pk[r] = (short)f2bf(acc[i][j][r]);
                    *(sh4*)(o2 + rowbase + n) = pk;
                }
        } else {
            ushort* outp = (z == 0) ? o0 : o1;
            // LDS bounce in 4 quarters of 32 rows -> coalesced 16B head-major stores
#pragma unroll
            for (int qd = 0; qd < 4; ++qd) {
                const int wmq = qd >> 1, a2 = qd & 1;
                __syncthreads();
                if (wm == wmq) {
#pragma unroll
                    for (int i2 = 0; i2 < 2; ++i2)
#pragma unroll
                        for (int j = 0; j < 4; ++j)
#pragma unroll
                            for (int r = 0; r < 4; ++r)
                                smem_s[(i2 * 16 + q * 4 + r) * 132 + wn * 64 + j * 16 + m16] =
                                    f2bf(acc[a2 * 2 + i2][j][r] * DN_SCALE);
                }
                __syncthreads();
#pragma unroll
                for (int t = 0; t < 2; ++t) {
                    int idx = tid + t * 256;
                    int rl = idx >> 4, ch = idx & 15;
                    frag_t v = *(const frag_t*)&smem_s[rl * 132 + ch * 8];
                    int n = (row0 & 4095) + wmq * 64 + a2 * 32 + rl;
                    int h = (col0 >> 6) + (ch >> 3);
                    int dh = (ch & 7) * 8;
                    *(frag_t*)(outp + ((size_t)((b << 4) + h) * 4096 + n) * 64 + dh) = v;
                }
            }
        }
    } else {
#pragma unroll
        for (int i = 0; i < 4; ++i)
#pragma unroll
            for (int j = 0; j < 4; ++j)
#pragma unroll
                for (int r = 0; r < 4; ++r) {
                    int row = row0 + wm * 64 + i * 16 + q * 4 + r;
                    int col = col0 + wn * 64 + j * 16 + m16;
                    size_t off = (size_t)row * 1024 + col;
                    yres[off] = acc[i][j][r] + bo[col] + xres[off];
                }
    }
}

// ---------------------------------------------------------------------------
// k-stab via MFMA (hi-only: stab cancels analytically except the 1e-4 EPS term)
// grid: (Nn/64, BH), block 256 (4 waves x 16 rows)
// ---------------------------------------------------------------------------
__global__ __launch_bounds__(256) void kstab_mfma_kernel(
    const ushort* __restrict__ kb, const ushort* __restrict__ pb,
    unsigned* __restrict__ stab_enc)
{
    const int n0 = blockIdx.x * 64;
    const int bh = blockIdx.y;
    const int tid = threadIdx.x;
    const int lane = tid & 63, w = tid >> 6;
    const int q = lane >> 4, m16 = lane & 15;

    __shared__ ushort ks_s[64 * 72];
    __shared__ ushort pj_s[64 * 72];

#pragma unroll
    for (int t = 0; t < 2; ++t) {
        int idx = tid + t * 256;
        int r = idx >> 3, s = idx & 7;
        *(frag_t*)&ks_s[r * 72 + s * 8] =
            *(const frag_t*)(kb + ((size_t)bh * Nn + n0 + r) * 64 + s * 8);
    }
    __syncthreads();

    frag_t aq[2];
#pragma unroll
    for (int s = 0; s < 2; ++s)
        aq[s] = *(const frag_t*)&ks_s[(w * 16 + m16) * 72 + s * 32 + q * 8];

    float mx = -3.0e38f;
#pragma unroll
    for (int mc = 0; mc < 5; ++mc) {
        __syncthreads();
#pragma unroll
        for (int t = 0; t < 2; ++t) {
            int idx = tid + t * 256;
            int r = idx >> 3, cc = idx & 7;   // hi half only
            *(frag_t*)&pj_s[r * 72 + cc * 8] =
                *(const frag_t*)(pb + ((size_t)mc * 64 + r) * 128 + cc * 8);
        }
        __syncthreads();
#pragma unroll
        for (int tm = 0; tm < 4; ++tm) {
            const int t = mc * 4 + tm;
            if (t > 16) continue;
            f32x4 sa = (f32x4){0.f, 0.f, 0.f, 0.f};
#pragma unroll
            for (int s = 0; s < 2; ++s) {
                frag_t bhi = *(const frag_t*)&pj_s[(tm * 16 + m16) * 72 + s * 32 + q * 8];
                sa = __builtin_amdgcn_mfma_f32_16x16x32_bf16(aq[s], bhi, sa, 0, 0, 0);
            }
            bool v = (t < 16) || (m16 < 10);
            if (v) {
#pragma unroll
                for (int r = 0; r < 4; ++r) mx = fmaxf(mx, sa[r]);
            }
        }
    }
    mx = fmaxf(mx, __shfl_xor(mx, 1));
    mx = fmaxf(mx, __shfl_xor(mx, 2));
    mx = fmaxf(mx, __shfl_xor(mx, 4));
    mx = fmaxf(mx, __shfl_xor(mx, 8));
    mx = fmaxf(mx, __shfl_xor(mx, 16));
    mx = fmaxf(mx, __shfl_xor(mx, 32));
    if (lane == 0) atomicMax(stab_enc + bh, fenc(mx));
}

// ---------------------------------------------------------------------------
// ctx via MFMA (unchanged from R2, verified)
// ---------------------------------------------------------------------------
__global__ __launch_bounds__(256) void ctx_mfma_kernel(
    const ushort* __restrict__ kb, const ushort* __restrict__ vT,
    const ushort* __restrict__ pb, const float* __restrict__ diagk,
    const unsigned* __restrict__ stab_enc,
    float* __restrict__ ctx, float* __restrict__ ksum)
{
    const int m0 = blockIdx.x * 64;
    const int nb = blockIdx.y;
    const int bh = blockIdx.z;
    const int tid = threadIdx.x;
    const int lane = tid & 63, w = tid >> 6;
    const int q = lane >> 4, m16 = lane & 15;
    const float kst = fdec(stab_enc[bh]);

    __shared__ ushort ks_s[32 * 72];
    __shared__ ushort pj_s[64 * 136];
    __shared__ ushort kf_s[64 * 40];
    __shared__ ushort vt_s[64 * 40];
    __shared__ float  diag_s[32];

    for (int u = tid; u < 1024; u += 256) {
        int r = u >> 4, c = (u & 15) * 8;
        *(frag_t*)&pj_s[r * 136 + c] = *(const frag_t*)(pb + (size_t)(m0 + r) * 128 + c);
    }

    f32x4 acc_c[4];
#pragma unroll
    for (int j = 0; j < 4; ++j) acc_c[j] = (f32x4){0.f, 0.f, 0.f, 0.f};
    float ksacc[2] = {0.f, 0.f};

    const int tn  = w & 1;
    const int tmb = (w >> 1) * 2;

    const int srow_k = tid >> 3, sseg_k = tid & 7;
    const int srow_v = tid >> 2, sseg_v = tid & 3;
    const size_t kbase = ((size_t)bh * Nn + nb * 1024 + srow_k) * 64 + sseg_k * 8;
    const size_t vbase = ((size_t)bh * 64 + srow_v) * Nn + nb * 1024 + sseg_v * 8;
    const float* dgp = diagk + (size_t)bh * Nn + nb * 1024;

    frag_t kreg = *(const frag_t*)(kb + kbase);
    frag_t vreg = *(const frag_t*)(vT + vbase);
    float4 dreg;
    if (tid < 8) dreg = *(const float4*)(dgp + tid * 4);

    for (int t = 0; t < 32; ++t) {
        __syncthreads();
        *(frag_t*)&ks_s[srow_k * 72 + sseg_k * 8] = kreg;
        *(frag_t*)&vt_s[srow_v * 40 + sseg_v * 8] = vreg;
        if (tid < 8) *(float4*)&diag_s[tid * 4] = dreg;
        __syncthreads();
        if (t < 31) {
            kreg = *(const frag_t*)(kb + kbase + (size_t)(t + 1) * 2048);
            vreg = *(const frag_t*)(vT + vbase + (size_t)(t + 1) * 32);
            if (tid < 8) dreg = *(const float4*)(dgp + (t + 1) * 32 + tid * 4);
        }

        f32x4 sa[2];
        sa[0] = (f32x4){0.f, 0.f, 0.f, 0.f};
        sa[1] = (f32x4){0.f, 0.f, 0.f, 0.f};
#pragma unroll
        for (int s = 0; s < 2; ++s) {
            frag_t a = *(const frag_t*)&ks_s[(tn * 16 + m16) * 72 + s * 32 + q * 8];
#pragma unroll
            for (int jj = 0; jj < 2; ++jj) {
                const ushort* prow = &pj_s[((tmb + jj) * 16 + m16) * 136 + s * 32 + q * 8];
                frag_t bhi = *(const frag_t*)prow;
                frag_t blo = *(const frag_t*)(prow + 64);
                sa[jj] = __builtin_amdgcn_mfma_f32_16x16x32_bf16(a, bhi, sa[jj], 0, 0, 0);
                sa[jj] = __builtin_amdgcn_mfma_f32_16x16x32_bf16(a, blo, sa[jj], 0, 0, 0);
            }
        }

#pragma unroll
        for (int jj = 0; jj < 2; ++jj) {
            int m_l = (tmb + jj) * 16 + m16;
            bool valid = (m0 + m_l) < Mm;
            sh4 pk;
            float vsum = 0.f;
#pragma unroll
            for (int r = 0; r < 4; ++r) {
                int n_l = tn * 16 + q * 4 + r;
                float val = valid ? RATIO * (__expf(sa[jj][r] - diag_s[n_l] - kst) + EPS_FAVOR) : 0.f;
                ushort hb = f2bf(val);
                pk[r] = (short)hb;
                vsum += bf2f(hb);
            }
            ksacc[jj] += vsum;
            *(sh4*)&kf_s[m_l * 40 + tn * 16 + q * 4] = pk;
        }
        __syncthreads();

        {
            frag_t a = *(const frag_t*)&kf_s[(w * 16 + m16) * 40 + q * 8];
#pragma unroll
            for (int j = 0; j < 4; ++j) {
                frag_t b = *(const frag_t*)&vt_s[(j * 16 + m16) * 40 + q * 8];
                acc_c[j] = __builtin_amdgcn_mfma_f32_16x16x32_bf16(a, b, acc_c[j], 0, 0, 0);
            }
        }
    }

#pragma unroll
    for (int j = 0; j < 4; ++j)
#pragma unroll
        for (int r = 0; r < 4; ++r) {
            int m = m0 + w * 16 + q * 4 + r;
            if (m < Mm)
                atomicAdd(&ctx[((size_t)bh * Mm + m) * 64 + j * 16 + m16], acc_c[j][r]);
        }
#pragma unroll
    for (int jj = 0; jj < 2; ++jj) {
        float v = ksacc[jj];
        v += __shfl_xor(v, 16);
        v += __shfl_xor(v, 32);
        int m = m0 + (tmb + jj) * 16 + m16;
        if (q == 0 && m < Mm) atomicAdd(&ksum[(size_t)bh * Mm + m], v);
    }
}

// ---------------------------------------------------------------------------
// q-side via MFMA (unchanged from R2, verified)
// ---------------------------------------------------------------------------
__global__ __launch_bounds__(256) void qout_mfma_kernel(
    const ushort* __restrict__ qb, const ushort* __restrict__ pb,
    const ushort* __restrict__ cT, const float* __restrict__ ksum,
    ushort* __restrict__ attnb)
{
    const int n0 = blockIdx.x * 64;
    const int bh = blockIdx.y;
    const int b = bh >> 4, h = bh & 15;
    const int tid = threadIdx.x;
    const int lane = tid & 63, w = tid >> 6;
    const int q = lane >> 4, m16 = lane & 15;

    __shared__ ushort qs_s[64 * 72];
    __shared__ ushort pj_s[64 * 136];
    __shared__ ushort qf_s[64 * 328];
    __shared__ float  diag_s[64];
    __shared__ float  ksum_s[320];

#pragma unroll
    for (int t = 0; t < 2; ++t) {
        int idx = tid + t * 256;
        int r = idx >> 3, s = idx & 7;
        *(frag_t*)&qs_s[r * 72 + s * 8] =
            *(const frag_t*)(qb + ((size_t)bh * Nn + n0 + r) * 64 + s * 8);
    }
    for (int m = tid; m < 320; m += 256)
        ksum_s[m] = (m < Mm) ? ksum[(size_t)bh * Mm + m] : 0.f;
    __syncthreads();
    if (tid < 64) {
        float s = 0.f;
#pragma unroll 8
        for (int k = 0; k < 64; ++k) { float f = bf2f(qs_s[tid * 72 + k]); s += f * f; }
        diag_s[tid] = 0.5f * s;
    }

    frag_t aq[2];
#pragma unroll
    for (int s = 0; s < 2; ++s)
        aq[s] = *(const frag_t*)&qs_s[(w * 16 + m16) * 72 + s * 32 + q * 8];

    f32x4 sA[20];
#pragma unroll
    for (int t = 0; t < 20; ++t) sA[t] = (f32x4){0.f, 0.f, 0.f, 0.f};

#pragma unroll
    for (int mc = 0; mc < 5; ++mc) {
        __syncthreads();
#pragma unroll
        for (int t = 0; t < 4; ++t) {
            int idx = tid + t * 256;
            int r = idx >> 4, c = idx & 15;
            *(frag_t*)&pj_s[r * 136 + c * 8] =
                *(const frag_t*)(pb + ((size_t)mc * 64 + r) * 128 + c * 8);
        }
        __syncthreads();
#pragma unroll
        for (int tm = 0; tm < 4; ++tm) {
#pragma unroll
            for (int s = 0; s < 2; ++s) {
                const ushort* pr = &pj_s[(tm * 16 + m16) * 136 + s * 32 + q * 8];
                frag_t bhi = *(const frag_t*)pr;
                frag_t blo = *(const frag_t*)(pr + 64);
                sA[mc * 4 + tm] = __builtin_amdgcn_mfma_f32_16x16x32_bf16(aq[s], bhi, sA[mc * 4 + tm], 0, 0, 0);
                sA[mc * 4 + tm] = __builtin_amdgcn_mfma_f32_16x16x32_bf16(aq[s], blo, sA[mc * 4 + tm], 0, 0, 0);
            }
        }
    }

    float mx[4] = {-3.0e38f, -3.0e38f, -3.0e38f, -3.0e38f};
#pragma unroll
    for (int t = 0; t < 17; ++t) {
        bool v = (t < 16) || (m16 < 10);
        if (v) {
#pragma unroll
            for (int r = 0; r < 4; ++r) mx[r] = fmaxf(mx[r], sA[t][r]);
        }
    }
#pragma unroll
    for (int r = 0; r < 4; ++r) {
        float v = mx[r];
        v = fmaxf(v, __shfl_xor(v, 1));
        v = fmaxf(v, __shfl_xor(v, 2));
        v = fmaxf(v, __shfl_xor(v, 4));
        v = fmaxf(v, __shfl_xor(v, 8));
        mx[r] = v;
    }
    float dg[4];
#pragma unroll
    for (int r = 0; r < 4; ++r) dg[r] = diag_s[w * 16 + q * 4 + r];

    float ds[4] = {0.f, 0.f, 0.f, 0.f};
#pragma unroll
    for (int t = 0; t < 20; ++t) {
        int m = t * 16 + m16;
        bool v = m < Mm;
        float ksm = ksum_s[m];
#pragma unroll
        for (int r = 0; r < 4; ++r) {
            ushort hb = 0;
            float val = 0.f;
            if (v) {
                hb = f2bf(RATIO * (__expf(sA[t][r] - dg[r] - mx[r]) + EPS_FAVOR));
                val = bf2f(hb);
            }
            ds[r] += val * ksm;
            qf_s[(w * 16 + q * 4 + r) * 328 + m] = hb;
        }
    }
#pragma unroll
    for (int r = 0; r < 4; ++r) {
        float v = ds[r];
        v += __shfl_xor(v, 1);
        v += __shfl_xor(v, 2);
        v += __shfl_xor(v, 4);
        v += __shfl_xor(v, 8);
        ds[r] = 1.0f / v;
    }

    f32x4 oA[4];
#pragma unroll
    for (int dt = 0; dt < 4; ++dt) oA[dt] = (f32x4){0.f, 0.f, 0.f, 0.f};

#pragma unroll
    for (int mc = 0; mc < 5; ++mc) {
        __syncthreads();
#pragma unroll
        for (int t = 0; t < 4; ++t) {
            int idx = tid + t * 256;
            int dd = idx >> 4, c = idx & 15;
            int off = (c >> 3) * 320 + mc * 64 + (c & 7) * 8;
            *(frag_t*)&pj_s[dd * 136 + c * 8] =
                *(const frag_t*)(cT + (size_t)bh * 40960 + (size_t)dd * 640 + off);
        }
        __syncthreads();
#pragma unroll
        for (int s = 0; s < 2; ++s) {
            frag_t a = *(const frag_t*)&qf_s[(w * 16 + m16) * 328 + mc * 64 + s * 32 + q * 8];
#pragma unroll
            for (int dt = 0; dt < 4; ++dt) {
                const ushort* pr = &pj_s[(dt * 16 + m16) * 136 + s * 32 + q * 8];
                frag_t bhi = *(const frag_t*)pr;
                frag_t blo = *(const frag_t*)(pr + 64);
                oA[dt] = __builtin_amdgcn_mfma_f32_16x16x32_bf16(a, bhi, oA[dt], 0, 0, 0);
                oA[dt] = __builtin_amdgcn_mfma_f32_16x16x32_bf16(a, blo, oA[dt], 0, 0, 0);
            }
        }
    }

#pragma unroll
    for (int dt = 0; dt < 4; ++dt)
#pragma unroll
        for (int r = 0; r < 4; ++r) {
            int n = n0 + w * 16 + q * 4 + r;
            attnb[((size_t)(b * Nn + n)) * Dd + h * 64 + dt * 16 + m16] =
                f2bf(oA[dt][r] * ds[r]);
        }
}

// ---------------------------------------------------------------------------
// LayerNorm: one block per row of 1024
// ---------------------------------------------------------------------------
__global__ __launch_bounds__(256) void ln_kernel(
    const float* __restrict__ y, const float* __restrict__ gamma,
    const float* __restrict__ beta, float* __restrict__ out)
{
    const int row = blockIdx.x;
    const int tid = threadIdx.x;
    float4 v = *(const float4*)(y + (size_t)row * Dd + tid * 4);
    float s = v.x + v.y + v.z + v.w;
    float q = v.x * v.x + v.y * v.y + v.z * v.z + v.w * v.w;
    __shared__ float rs[256], rq[256];
    rs[tid] = s; rq[tid] = q;
    __syncthreads();
    for (int off = 128; off > 0; off >>= 1) {
        if (tid < off) { rs[tid] += rs[tid + off]; rq[tid] += rq[tid + off]; }
        __syncthreads();
    }
    float mu = rs[0] * (1.0f / Dd);
    float var = rq[0] * (1.0f / Dd) - mu * mu;
    float rstd = rsqrtf(var + EPS_LN);
    float4 gm = *(const float4*)(gamma + tid * 4);
    float4 bt = *(const float4*)(beta + tid * 4);
    float4 o;
    o.x = (v.x - mu) * rstd * gm.x + bt.x;
    o.y = (v.y - mu) * rstd * gm.y + bt.y;
    o.z = (v.z - mu) * rstd * gm.z + bt.z;
    o.w = (v.w - mu) * rstd * gm.w + bt.w;
    *(float4*)(out + (size_t)row * Dd + tid * 4) = o;
}

// ---------------------------------------------------------------------------
extern "C" void kernel_launch(void* const* d_in, const int* in_sizes, int n_in,
                              void* d_out, int out_size, void* d_ws, size_t ws_size,
                              hipStream_t stream) {
    const float* x     = (const float*)d_in[0];
    const float* Wq    = (const float*)d_in[1];
    const float* Wk    = (const float*)d_in[2];
    const float* Wv    = (const float*)d_in[3];
    const float* Wo    = (const float*)d_in[4];
    const float* bo    = (const float*)d_in[5];
    const float* proj  = (const float*)d_in[6];
    const float* gamma = (const float*)d_in[7];
    const float* beta  = (const float*)d_in[8];
    float* out = (float*)d_out;

    const size_t TS = 16777216;           // tokens(16384) * 1024
    ushort* xb  = (ushort*)d_ws;          // x bf16; reused as attnb after QKV gemm
    ushort* qb  = xb + TS;
    ushort* kb  = qb + TS;
    ushort* vb  = kb + TS;                // holds vT [bh][64][4096] (written by gemm z==2)
    ushort* WTq = vb + TS;
    ushort* WTk = WTq + 1048576;
    ushort* WTv = WTk + 1048576;
    ushort* WTo = WTv + 1048576;
    float*  ctx  = (float*)(WTo + 1048576);         // BH*M*64 fp32
    float*  ksum = ctx + (size_t)BHh * Mm * DHh;    // BH*M
    unsigned* stab = (unsigned*)(ksum + (size_t)BHh * Mm);
    ushort* attnb = xb;                   // token-major bf16 attn (after gemm consumed xb)
    float*  yres  = (float*)qb;           // fp32, overlays qb+kb after qout
    ushort* vT     = vb;                  // [bh][64][4096] bf16, direct from gemm z==2
    float*  diagk  = (float*)WTq;         // 1 MB in the 2 MB WTq slot (after gemm)
    ushort* projb2 = WTk;                 // 80 KB in the 2 MB WTk slot (after gemm)
    ushort* ctxT   = vb;                  // [bh][64][640] bf16 hi|lo (after ctx consumed vT)

    hipMemsetAsync(ctx, 0, (size_t)BHh * Mm * DHh * sizeof(float), stream);
    hipMemsetAsync(ksum, 0, (size_t)BHh * Mm * sizeof(float), stream);
    hipMemsetAsync(stab, 0, BHh * sizeof(unsigned), stream);

    conv_x_kernel<<<8192, 256, 0, stream>>>(x, xb);
    conv_wt_kernel<<<dim3(16, 16, 4), 256, 0, stream>>>(Wq, Wk, Wv, Wo, WTq, WTk, WTv, WTo);

    gemm_bt<<<dim3(128, 8, 3), 256, 0, stream>>>(xb, WTq, WTk, WTv, qb, kb, vT,
                                                 nullptr, nullptr, nullptr, 0);

    diag_kernel<<<1024, 256, 0, stream>>>(kb, diagk);
    conv_proj_kernel<<<80, 256, 0, stream>>>(proj, projb2);

    kstab_mfma_kernel<<<dim3(Nn / 64, BHh), 256, 0, stream>>>(kb, projb2, stab);

    ctx_mfma_kernel<<<dim3(5, 4, BHh), 256, 0, stream>>>(kb, vT, projb2, diagk, stab,
                                                         ctx, ksum);

    ctx2bt_kernel<<<dim3(5, BHh), 256, 0, stream>>>(ctx, ctxT);

    qout_mfma_kernel<<<dim3(Nn / 64, BHh), 256, 0, stream>>>(qb, projb2, ctxT, ksum, attnb);

    gemm_bt<<<dim3(128, 8, 1), 256, 0, stream>>>(attnb, WTo, nullptr, nullptr,
                                                 nullptr, nullptr, nullptr, bo, x, yres, 1);
    ln_kernel<<<16384, 256, 0, stream>>>(yres, gamma, beta, out);
}

// Round 5
// 590.811 us; speedup vs baseline: 9.2780x; 1.2417x over previous
//
#include <hip/hip_runtime.h>
#include <hip/hip_bf16.h>
#include <math.h>

// Problem constants
#define Bb 4
#define Nn 4096
#define Hh 16
#define DHh 64
#define Mm 266
#define Dd 1024
#define BHh (Bb*Hh)

#define DN_SCALE 0.35355339059327373f   // 64^-0.25
#define RATIO 0.06131393394849658f      // 266^-0.5
#define EPS_FAVOR 1e-4f
#define EPS_LN 1e-5f

typedef __attribute__((ext_vector_type(8))) short frag_t;   // 8 x bf16
typedef __attribute__((ext_vector_type(4))) short sh4;      // 4 x bf16
typedef __attribute__((ext_vector_type(4))) float f32x4;

__device__ __forceinline__ ushort f2bf(float f) {
    unsigned u = __float_as_uint(f);
    return (ushort)((u + 0x7FFFu + ((u >> 16) & 1u)) >> 16);
}
__device__ __forceinline__ float bf2f(ushort h) {
    return __uint_as_float(((unsigned)h) << 16);
}
__device__ __forceinline__ unsigned fenc(float f) {
    unsigned u = __float_as_uint(f);
    return (u & 0x80000000u) ? ~u : (u | 0x80000000u);
}
__device__ __forceinline__ float fdec(unsigned e) {
    unsigned u = (e & 0x80000000u) ? (e ^ 0x80000000u) : ~e;
    return __uint_as_float(u);
}
__device__ __forceinline__ void gld16(const void* g, void* l) {
    __builtin_amdgcn_global_load_lds((const __attribute__((address_space(1))) unsigned int*)g,
                                     (__attribute__((address_space(3))) unsigned int*)l, 16, 0, 0);
}

// ---------------------------------------------------------------------------
// prep: x fp32 -> bf16
// ---------------------------------------------------------------------------
__global__ __launch_bounds__(256) void conv_x_kernel(const float* __restrict__ x,
                                                     ushort* __restrict__ xb) {
    size_t i = ((size_t)blockIdx.x * 256 + threadIdx.x) * 8;
    float4 f0 = *(const float4*)(x + i);
    float4 f1 = *(const float4*)(x + i + 4);
    uint4 o;
    o.x = (unsigned)f2bf(f0.x) | ((unsigned)f2bf(f0.y) << 16);
    o.y = (unsigned)f2bf(f0.z) | ((unsigned)f2bf(f0.w) << 16);
    o.z = (unsigned)f2bf(f1.x) | ((unsigned)f2bf(f1.y) << 16);
    o.w = (unsigned)f2bf(f1.z) | ((unsigned)f2bf(f1.w) << 16);
    *(uint4*)(xb + i) = o;
}

// prep: W[k][n] fp32 -> WT[n][k] bf16 (K-contiguous for the B^T GEMM)
__global__ __launch_bounds__(256) void conv_wt_kernel(
    const float* __restrict__ Wq, const float* __restrict__ Wk,
    const float* __restrict__ Wv, const float* __restrict__ Wo,
    ushort* __restrict__ Tq, ushort* __restrict__ Tk,
    ushort* __restrict__ Tv, ushort* __restrict__ To) {
    const int z = blockIdx.z;
    const float* W = z == 0 ? Wq : z == 1 ? Wk : z == 2 ? Wv : Wo;
    ushort* WT = z == 0 ? Tq : z == 1 ? Tk : z == 2 ? Tv : To;
    __shared__ float tls[64][65];
    const int tid = threadIdx.x;
    const int n0 = blockIdx.x * 64, k0 = blockIdx.y * 64;
    const int r = tid >> 2, seg = tid & 3;
#pragma unroll
    for (int i = 0; i < 4; ++i) {
        float4 f = *(const float4*)(W + (size_t)(k0 + r) * 1024 + n0 + seg * 16 + i * 4);
        tls[r][seg * 16 + i * 4 + 0] = f.x;
        tls[r][seg * 16 + i * 4 + 1] = f.y;
        tls[r][seg * 16 + i * 4 + 2] = f.z;
        tls[r][seg * 16 + i * 4 + 3] = f.w;
    }
    __syncthreads();
    const int nl = tid >> 2;
#pragma unroll
    for (int i = 0; i < 16; ++i)
        WT[(size_t)(n0 + nl) * 1024 + k0 + seg * 16 + i] = f2bf(tls[seg * 16 + i][nl]);
}

// prep: proj fp32 [266][64] -> bf16 hi/lo [320][128], zero-padded rows
__global__ __launch_bounds__(256) void conv_proj_kernel(const float* __restrict__ proj,
                                                        ushort* __restrict__ pb) {
    const int idx = blockIdx.x * 256 + threadIdx.x;   // 320*64 = 20480
    const int m = idx >> 6, k = idx & 63;
    float v = (m < Mm) ? proj[m * 64 + k] : 0.f;
    ushort hi = f2bf(v);
    float lo = v - bf2f(hi);
    pb[m * 128 + k] = hi;
    pb[m * 128 + 64 + k] = f2bf(lo);
}

// prep: diag[bh*4096+n] = 0.5 * sum_k kb[n][k]^2
__global__ __launch_bounds__(256) void diag_kernel(const ushort* __restrict__ kb,
                                                   float* __restrict__ dg) {
    const size_t i = (size_t)blockIdx.x * 256 + threadIdx.x;
    const ushort* p = kb + i * 64;
    float s = 0.f;
#pragma unroll
    for (int seg = 0; seg < 8; ++seg) {
        frag_t a = *(const frag_t*)(p + seg * 8);
#pragma unroll
        for (int j = 0; j < 8; ++j) { float f = bf2f((ushort)a[j]); s += f * f; }
    }
    dg[i] = 0.5f * s;
}

// prep: ctx fp32 [bh][m][64] -> ctxT hi/lo bf16 [bh][64 d][320 hi | 320 lo]
__global__ __launch_bounds__(256) void ctx2bt_kernel(const float* __restrict__ ctx,
                                                     ushort* __restrict__ cT) {
    const int mc = blockIdx.x;       // 0..4
    const int bh = blockIdx.y;
    const int tid = threadIdx.x;
    __shared__ float tls[64][65];
    const int r = tid >> 2, cs = tid & 3;
    const int gm = mc * 64 + r;
#pragma unroll
    for (int i = 0; i < 4; ++i) {
        float4 f = {0.f, 0.f, 0.f, 0.f};
        if (gm < Mm) f = *(const float4*)(ctx + ((size_t)bh * Mm + gm) * 64 + cs * 16 + i * 4);
        tls[r][cs * 16 + i * 4 + 0] = f.x;
        tls[r][cs * 16 + i * 4 + 1] = f.y;
        tls[r][cs * 16 + i * 4 + 2] = f.z;
        tls[r][cs * 16 + i * 4 + 3] = f.w;
    }
    __syncthreads();
    const int d = tid >> 2, ms = tid & 3;
    unsigned hi[8], lo[8];
#pragma unroll
    for (int j = 0; j < 8; ++j) {
        float v0 = tls[ms * 16 + j * 2][d];
        float v1 = tls[ms * 16 + j * 2 + 1][d];
        ushort h0 = f2bf(v0), h1 = f2bf(v1);
        ushort l0 = f2bf(v0 - bf2f(h0)), l1 = f2bf(v1 - bf2f(h1));
        hi[j] = (unsigned)h0 | ((unsigned)h1 << 16);
        lo[j] = (unsigned)l0 | ((unsigned)l1 << 16);
    }
    size_t base = (size_t)bh * 40960 + (size_t)d * 640 + mc * 64 + ms * 16;
    uint4 a = {hi[0], hi[1], hi[2], hi[3]};
    uint4 b = {hi[4], hi[5], hi[6], hi[7]};
    uint4 c = {lo[0], lo[1], lo[2], lo[3]};
    uint4 e = {lo[4], lo[5], lo[6], lo[7]};
    *(uint4*)(cT + base) = a;
    *(uint4*)(cT + base + 8) = b;
    *(uint4*)(cT + base + 320) = c;
    *(uint4*)(cT + base + 328) = e;
}

// ---------------------------------------------------------------------------
// 256x256 pipelined bf16 GEMM, 64 KiB static LDS (4 half-slot ring, BK=32).
// 8 waves (2Mx4N). Counted vmcnt (never 0 in steady state), raw barriers,
// XOR-swizzled LDS, setprio around the 32-MFMA cluster.
// mode 0: head-major bf16 out (z 0,1 scaled; z==2 writes transposed vT)
// mode 1: fp32 + bias + residual
// ---------------------------------------------------------------------------
__global__ __launch_bounds__(512, 2) void gemm256(
    const ushort* __restrict__ A,
    const ushort* __restrict__ W0, const ushort* __restrict__ W1, const ushort* __restrict__ W2,
    ushort* __restrict__ o0, ushort* __restrict__ o1, ushort* __restrict__ o2,
    const float* __restrict__ bo, const float* __restrict__ xres, float* __restrict__ yres,
    int mode)
{
    __shared__ ushort smem[32768];   // 4 half-slots x (A 4096 | B 4096) ushorts
    const int tid = threadIdx.x;
    const int lane = tid & 63, w = tid >> 6;
    const int q = lane >> 4, m16 = lane & 15;
    const int wm = w >> 2, wn = w & 3;
    const int row0 = blockIdx.x * 256, col0 = blockIdx.y * 256;
    const int z = blockIdx.z;
    const ushort* WT = (mode == 0) ? (z == 0 ? W0 : z == 1 ? W1 : W2) : W0;

    // staging: 512 thr x 16B = one 128-row x 32-k half (A or B) per gld16
    const int srow = tid >> 2, sseg = tid & 3;
    const int ksw = (sseg ^ ((srow >> 1) & 3)) * 8;   // pre-swizzled SOURCE k-chunk
    const int dst = tid * 8;                          // linear LDS dest
    const int sq  = (q ^ ((m16 >> 1) & 3)) * 8;      // swizzled READ k-chunk

#define STG(T_) do {                                                          \
        int s0_ = (2 * (T_)) & 3, s1_ = (2 * (T_) + 1) & 3;                   \
        gld16(A  + (size_t)(row0 + srow) * 1024 + (T_) * 32 + ksw,            \
              smem + s0_ * 8192 + dst);                                       \
        gld16(WT + (size_t)(col0 + srow) * 1024 + (T_) * 32 + ksw,            \
              smem + s0_ * 8192 + 4096 + dst);                                \
        gld16(A  + (size_t)(row0 + 128 + srow) * 1024 + (T_) * 32 + ksw,      \
              smem + s1_ * 8192 + dst);                                       \
        gld16(WT + (size_t)(col0 + 128 + srow) * 1024 + (T_) * 32 + ksw,      \
              smem + s1_ * 8192 + 4096 + dst);                                \
    } while (0)

    f32x4 acc[8][4];
#pragma unroll
    for (int i = 0; i < 8; ++i)
#pragma unroll
        for (int j = 0; j < 4; ++j) acc[i][j] = (f32x4){0.f, 0.f, 0.f, 0.f};

    STG(0);
    STG(1);

    for (int kt = 0; kt < 32; ++kt) {
        // tile kt's 4 loads are the oldest; tile kt+1's 4 may stay in flight
        if (kt < 31) { asm volatile("s_waitcnt vmcnt(4)" ::: "memory"); }
        else         { asm volatile("s_waitcnt vmcnt(0)" ::: "memory"); }
        __builtin_amdgcn_sched_barrier(0);
        __builtin_amdgcn_s_barrier();
        __builtin_amdgcn_sched_barrier(0);

        const ushort* As_ = smem + (((2 * kt + wm) & 3) * 8192);
        const ushort* Bs_ = smem + (((2 * kt + (wn >> 1)) & 3) * 8192) + 4096;
        frag_t af[8], bf[4];
#pragma unroll
        for (int i = 0; i < 8; ++i)
            af[i] = *(const frag_t*)&As_[(i * 16 + m16) * 32 + sq];
#pragma unroll
        for (int j = 0; j < 4; ++j)
            bf[j] = *(const frag_t*)&Bs_[((wn & 1) * 64 + j * 16 + m16) * 32 + sq];

        asm volatile("s_waitcnt lgkmcnt(0)" ::: "memory");
        __builtin_amdgcn_sched_barrier(0);
        __builtin_amdgcn_s_barrier();        // all waves' reads retired
        __builtin_amdgcn_sched_barrier(0);

        if (kt + 2 < 32) STG(kt + 2);        // overwrites slots just read - safe
        __builtin_amdgcn_sched_barrier(0);

        __builtin_amdgcn_s_setprio(1);
#pragma unroll
        for (int i = 0; i < 8; ++i)
#pragma unroll
            for (int j = 0; j < 4; ++j)
                acc[i][j] = __builtin_amdgcn_mfma_f32_16x16x32_bf16(af[i], bf[j], acc[i][j], 0, 0, 0);
        __builtin_amdgcn_s_setprio(0);
        __builtin_amdgcn_sched_barrier(0);
    }
#undef STG

    const int b = row0 >> 12;   // 256-row tile sits inside one batch
    if (mode == 0) {
        if (z == 2) {
            // direct transposed write: vT[((b*16+h)*64+dh)*4096 + n], 8B per lane
#pragma unroll
            for (int i = 0; i < 8; ++i)
#pragma unroll
                for (int j = 0; j < 4; ++j) {
                    int col = col0 + wn * 64 + j * 16 + m16;
                    size_t rowbase = ((size_t)((b << 4) + (col >> 6)) * 64 + (col & 63)) * 4096;
                    int n = (row0 & 4095) + wm * 128 + i * 16 + q * 4;
                    sh4 pk;
#pragma unroll
                    for (int r = 0; r < 4; ++r) pk[r] = (short)f2bf(acc[i][j][r]);
                    *(sh4*)(o2 + rowbase + n) = pk;
                }
        } else {
            ushort* outp = (z == 0) ? o0 : o1;
            // LDS bounce in 4 chunks of 64 rows -> coalesced 16B head-major stores
#pragma unroll
            for (int c = 0; c < 4; ++c) {
                __builtin_amdgcn_s_barrier();
                if (wm == (c >> 1)) {
#pragma unroll
                    for (int i2 = 0; i2 < 4; ++i2) {
                        int i = (c & 1) * 4 + i2;
#pragma unroll
                        for (int j = 0; j < 4; ++j)
#pragma unroll
                            for (int r = 0; r < 4; ++r)
                                smem[(i2 * 16 + q * 4 + r) * 264 + wn * 64 + j * 16 + m16] =
                                    f2bf(acc[i][j][r] * DN_SCALE);
                    }
                }
                __builtin_amdgcn_s_barrier();
#pragma unroll
                for (int it = 0; it < 4; ++it) {
                    int idx = it * 512 + tid;
                    int lr = idx >> 5, ch = idx & 31;
                    frag_t v = *(const frag_t*)&smem[lr * 264 + ch * 8];
                    int n = (row0 & 4095) + c * 64 + lr;
                    int h = (col0 >> 6) + (ch >> 3);
                    int dh = (ch & 7) * 8;
                    *(frag_t*)(outp + ((size_t)((b << 4) + h) * 4096 + n) * 64 + dh) = v;
                }
            }
        }
    } else {
#pragma unroll
        for (int i = 0; i < 8; ++i)
#pragma unroll
            for (int j = 0; j < 4; ++j)
#pragma unroll
                for (int r = 0; r < 4; ++r) {
                    int row = row0 + wm * 128 + i * 16 + q * 4 + r;
                    int col = col0 + wn * 64 + j * 16 + m16;
                    size_t off = (size_t)row * 1024 + col;
                    yres[off] = acc[i][j][r] + bo[col] + xres[off];
                }
    }
}

// ---------------------------------------------------------------------------
// k-stab via MFMA, 256 rows/block (hi-only; stab cancels analytically except
// the 1e-4 EPS term).  grid: (Nn/256, BH), block 256 (4 waves x 64 rows)
// ---------------------------------------------------------------------------
__global__ __launch_bounds__(256) void kstab_mfma_kernel(
    const ushort* __restrict__ kb, const ushort* __restrict__ pb,
    unsigned* __restrict__ stab_enc)
{
    const int n0 = blockIdx.x * 256;
    const int bh = blockIdx.y;
    const int tid = threadIdx.x;
    const int lane = tid & 63, w = tid >> 6;
    const int q = lane >> 4, m16 = lane & 15;

    __shared__ ushort ks_s[256 * 72];
    __shared__ ushort pj_s[64 * 72];

#pragma unroll
    for (int t = 0; t < 8; ++t) {
        int idx = tid + t * 256;
        int r = idx >> 3, s = idx & 7;
        *(frag_t*)&ks_s[r * 72 + s * 8] =
            *(const frag_t*)(kb + ((size_t)bh * Nn + n0 + r) * 64 + s * 8);
    }
    __syncthreads();

    frag_t aq[4][2];
#pragma unroll
    for (int g = 0; g < 4; ++g)
#pragma unroll
        for (int s = 0; s < 2; ++s)
            aq[g][s] = *(const frag_t*)&ks_s[(w * 64 + g * 16 + m16) * 72 + s * 32 + q * 8];

    float mx = -3.0e38f;
#pragma unroll
    for (int mc = 0; mc < 5; ++mc) {
        __syncthreads();
#pragma unroll
        for (int t = 0; t < 2; ++t) {
            int idx = tid + t * 256;
            int r = idx >> 3, cc = idx & 7;   // hi half only
            *(frag_t*)&pj_s[r * 72 + cc * 8] =
                *(const frag_t*)(pb + ((size_t)mc * 64 + r) * 128 + cc * 8);
        }
        __syncthreads();
#pragma unroll
        for (int tm = 0; tm < 4; ++tm) {
            const int t = mc * 4 + tm;
            if (t > 16) continue;
            frag_t bh0 = *(const frag_t*)&pj_s[(tm * 16 + m16) * 72 + q * 8];
            frag_t bh1 = *(const frag_t*)&pj_s[(tm * 16 + m16) * 72 + 32 + q * 8];
            bool v = (t < 16) || (m16 < 10);
#pragma unroll
            for (int g = 0; g < 4; ++g) {
                f32x4 sa = (f32x4){0.f, 0.f, 0.f, 0.f};
                sa = __builtin_amdgcn_mfma_f32_16x16x32_bf16(aq[g][0], bh0, sa, 0, 0, 0);
                sa = __builtin_amdgcn_mfma_f32_16x16x32_bf16(aq[g][1], bh1, sa, 0, 0, 0);
                if (v) {
#pragma unroll
                    for (int r = 0; r < 4; ++r) mx = fmaxf(mx, sa[r]);
                }
            }
        }
    }
    mx = fmaxf(mx, __shfl_xor(mx, 1));
    mx = fmaxf(mx, __shfl_xor(mx, 2));
    mx = fmaxf(mx, __shfl_xor(mx, 4));
    mx = fmaxf(mx, __shfl_xor(mx, 8));
    mx = fmaxf(mx, __shfl_xor(mx, 16));
    mx = fmaxf(mx, __shfl_xor(mx, 32));
    if (lane == 0) atomicMax(stab_enc + bh, fenc(mx));
}

// ---------------------------------------------------------------------------
// ctx via MFMA (unchanged, verified)
// ---------------------------------------------------------------------------
__global__ __launch_bounds__(256) void ctx_mfma_kernel(
    const ushort* __restrict__ kb, const ushort* __restrict__ vT,
    const ushort* __restrict__ pb, const float* __restrict__ diagk,
    const unsigned* __restrict__ stab_enc,
    float* __restrict__ ctx, float* __restrict__ ksum)
{
    const int m0 = blockIdx.x * 64;
    const int nb = blockIdx.y;
    const int bh = blockIdx.z;
    const int tid = threadIdx.x;
    const int lane = tid & 63, w = tid >> 6;
    const int q = lane >> 4, m16 = lane & 15;
    const float kst = fdec(stab_enc[bh]);

    __shared__ ushort ks_s[32 * 72];
    __shared__ ushort pj_s[64 * 136];
    __shared__ ushort kf_s[64 * 40];
    __shared__ ushort vt_s[64 * 40];
    __shared__ float  diag_s[32];

    for (int u = tid; u < 1024; u += 256) {
        int r = u >> 4, c = (u & 15) * 8;
        *(frag_t*)&pj_s[r * 136 + c] = *(const frag_t*)(pb + (size_t)(m0 + r) * 128 + c);
    }

    f32x4 acc_c[4];
#pragma unroll
    for (int j = 0; j < 4; ++j) acc_c[j] = (f32x4){0.f, 0.f, 0.f, 0.f};
    float ksacc[2] = {0.f, 0.f};

    const int tn  = w & 1;
    const int tmb = (w >> 1) * 2;

    const int srow_k = tid >> 3, sseg_k = tid & 7;
    const int srow_v = tid >> 2, sseg_v = tid & 3;
    const size_t kbase = ((size_t)bh * Nn + nb * 1024 + srow_k) * 64 + sseg_k * 8;
    const size_t vbase = ((size_t)bh * 64 + srow_v) * Nn + nb * 1024 + sseg_v * 8;
    const float* dgp = diagk + (size_t)bh * Nn + nb * 1024;

    frag_t kreg = *(const frag_t*)(kb + kbase);
    frag_t vreg = *(const frag_t*)(vT + vbase);
    float4 dreg;
    if (tid < 8) dreg = *(const float4*)(dgp + tid * 4);

    for (int t = 0; t < 32; ++t) {
        __syncthreads();
        *(frag_t*)&ks_s[srow_k * 72 + sseg_k * 8] = kreg;
        *(frag_t*)&vt_s[srow_v * 40 + sseg_v * 8] = vreg;
        if (tid < 8) *(float4*)&diag_s[tid * 4] = dreg;
        __syncthreads();
        if (t < 31) {
            kreg = *(const frag_t*)(kb + kbase + (size_t)(t + 1) * 2048);
            vreg = *(const frag_t*)(vT + vbase + (size_t)(t + 1) * 32);
            if (tid < 8) dreg = *(const float4*)(dgp + (t + 1) * 32 + tid * 4);
        }

        f32x4 sa[2];
        sa[0] = (f32x4){0.f, 0.f, 0.f, 0.f};
        sa[1] = (f32x4){0.f, 0.f, 0.f, 0.f};
#pragma unroll
        for (int s = 0; s < 2; ++s) {
            frag_t a = *(const frag_t*)&ks_s[(tn * 16 + m16) * 72 + s * 32 + q * 8];
#pragma unroll
            for (int jj = 0; jj < 2; ++jj) {
                const ushort* prow = &pj_s[((tmb + jj) * 16 + m16) * 136 + s * 32 + q * 8];
                frag_t bhi = *(const frag_t*)prow;
                frag_t blo = *(const frag_t*)(prow + 64);
                sa[jj] = __builtin_amdgcn_mfma_f32_16x16x32_bf16(a, bhi, sa[jj], 0, 0, 0);
                sa[jj] = __builtin_amdgcn_mfma_f32_16x16x32_bf16(a, blo, sa[jj], 0, 0, 0);
            }
        }

#pragma unroll
        for (int jj = 0; jj < 2; ++jj) {
            int m_l = (tmb + jj) * 16 + m16;
            bool valid = (m0 + m_l) < Mm;
            sh4 pk;
            float vsum = 0.f;
#pragma unroll
            for (int r = 0; r < 4; ++r) {
                int n_l = tn * 16 + q * 4 + r;
                float val = valid ? RATIO * (__expf(sa[jj][r] - diag_s[n_l] - kst) + EPS_FAVOR) : 0.f;
                ushort hb = f2bf(val);
                pk[r] = (short)hb;
                vsum += bf2f(hb);
            }
            ksacc[jj] += vsum;
            *(sh4*)&kf_s[m_l * 40 + tn * 16 + q * 4] = pk;
        }
        __syncthreads();

        {
            frag_t a = *(const frag_t*)&kf_s[(w * 16 + m16) * 40 + q * 8];
#pragma unroll
            for (int j = 0; j < 4; ++j) {
                frag_t b = *(const frag_t*)&vt_s[(j * 16 + m16) * 40 + q * 8];
                acc_c[j] = __builtin_amdgcn_mfma_f32_16x16x32_bf16(a, b, acc_c[j], 0, 0, 0);
            }
        }
    }

#pragma unroll
    for (int j = 0; j < 4; ++j)
#pragma unroll
        for (int r = 0; r < 4; ++r) {
            int m = m0 + w * 16 + q * 4 + r;
            if (m < Mm)
                atomicAdd(&ctx[((size_t)bh * Mm + m) * 64 + j * 16 + m16], acc_c[j][r]);
        }
#pragma unroll
    for (int jj = 0; jj < 2; ++jj) {
        float v = ksacc[jj];
        v += __shfl_xor(v, 16);
        v += __shfl_xor(v, 32);
        int m = m0 + (tmb + jj) * 16 + m16;
        if (q == 0 && m < Mm) atomicAdd(&ksum[(size_t)bh * Mm + m], v);
    }
}

// ---------------------------------------------------------------------------
// q-side via MFMA (unchanged, verified)
// ---------------------------------------------------------------------------
__global__ __launch_bounds__(256) void qout_mfma_kernel(
    const ushort* __restrict__ qb, const ushort* __restrict__ pb,
    const ushort* __restrict__ cT, const float* __restrict__ ksum,
    ushort* __restrict__ attnb)
{
    const int n0 = blockIdx.x * 64;
    const int bh = blockIdx.y;
    const int b = bh >> 4, h = bh & 15;
    const int tid = threadIdx.x;
    const int lane = tid & 63, w = tid >> 6;
    const int q = lane >> 4, m16 = lane & 15;

    __shared__ ushort qs_s[64 * 72];
    __shared__ ushort pj_s[64 * 136];
    __shared__ ushort qf_s[64 * 328];
    __shared__ float  diag_s[64];
    __shared__ float  ksum_s[320];

#pragma unroll
    for (int t = 0; t < 2; ++t) {
        int idx = tid + t * 256;
        int r = idx >> 3, s = idx & 7;
        *(frag_t*)&qs_s[r * 72 + s * 8] =
            *(const frag_t*)(qb + ((size_t)bh * Nn + n0 + r) * 64 + s * 8);
    }
    for (int m = tid; m < 320; m += 256)
        ksum_s[m] = (m < Mm) ? ksum[(size_t)bh * Mm + m] : 0.f;
    __syncthreads();
    if (tid < 64) {
        float s = 0.f;
#pragma unroll 8
        for (int k = 0; k < 64; ++k) { float f = bf2f(qs_s[tid * 72 + k]); s += f * f; }
        diag_s[tid] = 0.5f * s;
    }

    frag_t aq[2];
#pragma unroll
    for (int s = 0; s < 2; ++s)
        aq[s] = *(const frag_t*)&qs_s[(w * 16 + m16) * 72 + s * 32 + q * 8];

    f32x4 sA[20];
#pragma unroll
    for (int t = 0; t < 20; ++t) sA[t] = (f32x4){0.f, 0.f, 0.f, 0.f};

#pragma unroll
    for (int mc = 0; mc < 5; ++mc) {
        __syncthreads();
#pragma unroll
        for (int t = 0; t < 4; ++t) {
            int idx = tid + t * 256;
            int r = idx >> 4, c = idx & 15;
            *(frag_t*)&pj_s[r * 136 + c * 8] =
                *(const frag_t*)(pb + ((size_t)mc * 64 + r) * 128 + c * 8);
        }
        __syncthreads();
#pragma unroll
        for (int tm = 0; tm < 4; ++tm) {
#pragma unroll
            for (int s = 0; s < 2; ++s) {
                const ushort* pr = &pj_s[(tm * 16 + m16) * 136 + s * 32 + q * 8];
                frag_t bhi = *(const frag_t*)pr;
                frag_t blo = *(const frag_t*)(pr + 64);
                sA[mc * 4 + tm] = __builtin_amdgcn_mfma_f32_16x16x32_bf16(aq[s], bhi, sA[mc * 4 + tm], 0, 0, 0);
                sA[mc * 4 + tm] = __builtin_amdgcn_mfma_f32_16x16x32_bf16(aq[s], blo, sA[mc * 4 + tm], 0, 0, 0);
            }
        }
    }

    float mx[4] = {-3.0e38f, -3.0e38f, -3.0e38f, -3.0e38f};
#pragma unroll
    for (int t = 0; t < 17; ++t) {
        bool v = (t < 16) || (m16 < 10);
        if (v) {
#pragma unroll
            for (int r = 0; r < 4; ++r) mx[r] = fmaxf(mx[r], sA[t][r]);
        }
    }
#pragma unroll
    for (int r = 0; r < 4; ++r) {
        float v = mx[r];
        v = fmaxf(v, __shfl_xor(v, 1));
        v = fmaxf(v, __shfl_xor(v, 2));
        v = fmaxf(v, __shfl_xor(v, 4));
        v = fmaxf(v, __shfl_xor(v, 8));
        mx[r] = v;
    }
    float dg[4];
#pragma unroll
    for (int r = 0; r < 4; ++r) dg[r] = diag_s[w * 16 + q * 4 + r];

    float ds[4] = {0.f, 0.f, 0.f, 0.f};
#pragma unroll
    for (int t = 0; t < 20; ++t) {
        int m = t * 16 + m16;
        bool v = m < Mm;
        float ksm = ksum_s[m];
#pragma unroll
        for (int r = 0; r < 4; ++r) {
            ushort hb = 0;
            float val = 0.f;
            if (v) {
                hb = f2bf(RATIO * (__expf(sA[t][r] - dg[r] - mx[r]) + EPS_FAVOR));
                val = bf2f(hb);
            }
            ds[r] += val * ksm;
            qf_s[(w * 16 + q * 4 + r) * 328 + m] = hb;
        }
    }
#pragma unroll
    for (int r = 0; r < 4; ++r) {
        float v = ds[r];
        v += __shfl_xor(v, 1);
        v += __shfl_xor(v, 2);
        v += __shfl_xor(v, 4);
        v += __shfl_xor(v, 8);
        ds[r] = 1.0f / v;
    }

    f32x4 oA[4];
#pragma unroll
    for (int dt = 0; dt < 4; ++dt) oA[dt] = (f32x4){0.f, 0.f, 0.f, 0.f};

#pragma unroll
    for (int mc = 0; mc < 5; ++mc) {
        __syncthreads();
#pragma unroll
        for (int t = 0; t < 4; ++t) {
            int idx = tid + t * 256;
            int dd = idx >> 4, c = idx & 15;
            int off = (c >> 3) * 320 + mc * 64 + (c & 7) * 8;
            *(frag_t*)&pj_s[dd * 136 + c * 8] =
                *(const frag_t*)(cT + (size_t)bh * 40960 + (size_t)dd * 640 + off);
        }
        __syncthreads();
#pragma unroll
        for (int s = 0; s < 2; ++s) {
            frag_t a = *(const frag_t*)&qf_s[(w * 16 + m16) * 328 + mc * 64 + s * 32 + q * 8];
#pragma unroll
            for (int dt = 0; dt < 4; ++dt) {
                const ushort* pr = &pj_s[(dt * 16 + m16) * 136 + s * 32 + q * 8];
                frag_t bhi = *(const frag_t*)pr;
                frag_t blo = *(const frag_t*)(pr + 64);
                oA[dt] = __builtin_amdgcn_mfma_f32_16x16x32_bf16(a, bhi, oA[dt], 0, 0, 0);
                oA[dt] = __builtin_amdgcn_mfma_f32_16x16x32_bf16(a, blo, oA[dt], 0, 0, 0);
            }
        }
    }

#pragma unroll
    for (int dt = 0; dt < 4; ++dt)
#pragma unroll
        for (int r = 0; r < 4; ++r) {
            int n = n0 + w * 16 + q * 4 + r;
            attnb[((size_t)(b * Nn + n)) * Dd + h * 64 + dt * 16 + m16] =
                f2bf(oA[dt][r] * ds[r]);
        }
}

// ---------------------------------------------------------------------------
// LayerNorm: one block per row of 1024
// ---------------------------------------------------------------------------
__global__ __launch_bounds__(256) void ln_kernel(
    const float* __restrict__ y, const float* __restrict__ gamma,
    const float* __restrict__ beta, float* __restrict__ out)
{
    const int row = blockIdx.x;
    const int tid = threadIdx.x;
    float4 v = *(const float4*)(y + (size_t)row * Dd + tid * 4);
    float s = v.x + v.y + v.z + v.w;
    float q = v.x * v.x + v.y * v.y + v.z * v.z + v.w * v.w;
    __shared__ float rs[256], rq[256];
    rs[tid] = s; rq[tid] = q;
    __syncthreads();
    for (int off = 128; off > 0; off >>= 1) {
        if (tid < off) { rs[tid] += rs[tid + off]; rq[tid] += rq[tid + off]; }
        __syncthreads();
    }
    float mu = rs[0] * (1.0f / Dd);
    float var = rq[0] * (1.0f / Dd) - mu * mu;
    float rstd = rsqrtf(var + EPS_LN);
    float4 gm = *(const float4*)(gamma + tid * 4);
    float4 bt = *(const float4*)(beta + tid * 4);
    float4 o;
    o.x = (v.x - mu) * rstd * gm.x + bt.x;
    o.y = (v.y - mu) * rstd * gm.y + bt.y;
    o.z = (v.z - mu) * rstd * gm.z + bt.z;
    o.w = (v.w - mu) * rstd * gm.w + bt.w;
    *(float4*)(out + (size_t)row * Dd + tid * 4) = o;
}

// ---------------------------------------------------------------------------
extern "C" void kernel_launch(void* const* d_in, const int* in_sizes, int n_in,
                              void* d_out, int out_size, void* d_ws, size_t ws_size,
                              hipStream_t stream) {
    const float* x     = (const float*)d_in[0];
    const float* Wq    = (const float*)d_in[1];
    const float* Wk    = (const float*)d_in[2];
    const float* Wv    = (const float*)d_in[3];
    const float* Wo    = (const float*)d_in[4];
    const float* bo    = (const float*)d_in[5];
    const float* proj  = (const float*)d_in[6];
    const float* gamma = (const float*)d_in[7];
    const float* beta  = (const float*)d_in[8];
    float* out = (float*)d_out;

    const size_t TS = 16777216;           // tokens(16384) * 1024
    ushort* xb  = (ushort*)d_ws;          // x bf16; reused as attnb after QKV gemm
    ushort* qb  = xb + TS;
    ushort* kb  = qb + TS;
    ushort* vb  = kb + TS;                // holds vT [bh][64][4096] (gemm z==2 writes)
    ushort* WTq = vb + TS;
    ushort* WTk = WTq + 1048576;
    ushort* WTv = WTk + 1048576;
    ushort* WTo = WTv + 1048576;
    float*  ctx  = (float*)(WTo + 1048576);         // BH*M*64 fp32
    float*  ksum = ctx + (size_t)BHh * Mm * DHh;    // BH*M
    unsigned* stab = (unsigned*)(ksum + (size_t)BHh * Mm);
    ushort* attnb = xb;                   // token-major bf16 attn (after gemm consumed xb)
    float*  yres  = (float*)qb;           // fp32, overlays qb+kb after qout
    ushort* vT     = vb;                  // [bh][64][4096] bf16, direct from gemm z==2
    float*  diagk  = (float*)WTq;         // 1 MB in the 2 MB WTq slot (after gemm)
    ushort* projb2 = WTk;                 // 80 KB in the 2 MB WTk slot (after gemm)
    ushort* ctxT   = vb;                  // [bh][64][640] bf16 hi|lo (after ctx consumed vT)

    hipMemsetAsync(ctx, 0, (size_t)BHh * Mm * DHh * sizeof(float), stream);
    hipMemsetAsync(ksum, 0, (size_t)BHh * Mm * sizeof(float), stream);
    hipMemsetAsync(stab, 0, BHh * sizeof(unsigned), stream);

    conv_x_kernel<<<8192, 256, 0, stream>>>(x, xb);
    conv_wt_kernel<<<dim3(16, 16, 4), 256, 0, stream>>>(Wq, Wk, Wv, Wo, WTq, WTk, WTv, WTo);

    gemm256<<<dim3(64, 4, 3), 512, 0, stream>>>(xb, WTq, WTk, WTv, qb, kb, vT,
                                                nullptr, nullptr, nullptr, 0);

    diag_kernel<<<1024, 256, 0, stream>>>(kb, diagk);
    conv_proj_kernel<<<80, 256, 0, stream>>>(proj, projb2);

    kstab_mfma_kernel<<<dim3(Nn / 256, BHh), 256, 0, stream>>>(kb, projb2, stab);

    ctx_mfma_kernel<<<dim3(5, 4, BHh), 256, 0, stream>>>(kb, vT, projb2, diagk, stab,
                                                         ctx, ksum);

    ctx2bt_kernel<<<dim3(5, BHh), 256, 0, stream>>>(ctx, ctxT);

    qout_mfma_kernel<<<dim3(Nn / 64, BHh), 256, 0, stream>>>(qb, projb2, ctxT, ksum, attnb);

    gemm256<<<dim3(64, 4, 1), 512, 0, stream>>>(attnb, WTo, nullptr, nullptr,
                                                nullptr, nullptr, nullptr, bo, x, yres, 1);
    ln_kernel<<<16384, 256, 0, stream>>>(yres, gamma, beta, out);
}